// Round 3
// baseline (2419.991 us; speedup 1.0000x reference)
//
#include <hip/hip_runtime.h>

// Problem constants (fixed by the reference)
#define BD 8
#define SD 4096
#define DDIM 512
#define QD 8
#define CDN 1024
#define ROWS (BD * SD)              // 32768
#define QUANT_ELEMS (ROWS * DDIM)   // 16777216
#define IDX_OFF QUANT_ELEMS
#define LOSS_OFF (QUANT_ELEMS + ROWS * QD)

#define TPB 512
#define NWAVE (TPB / 64)            // 8 waves/block
#define BR 32                       // rows per block
// 3-MFMA split (ah*bh + al*bh + ah*bl): max dist error ~2e-3 << MARGIN/2.
#define MARGIN 0.25f

// ws layout (bytes)
#define WS_LOSS 0                   // 8 doubles
#define WS_FBCNT 64                 // 8 ints
#define WS_FBLIST 4096              // 32768 ints (128 KB)
#define WS_NORMS 0x40000            // 32 KB
#define WS_PKHI 0x100000            // 8 MB (all levels)
#define WS_PKLO 0x900000            // 8 MB
#define WS_RESID 0x1100000          // 64 MB

typedef __attribute__((ext_vector_type(8))) short short8;
typedef __attribute__((ext_vector_type(4))) float f32x4;

__device__ __forceinline__ ushort f2bf(float x) {
    unsigned u = __float_as_uint(x);
    u += 0x7fff + ((u >> 16) & 1);          // RTNE
    return (ushort)(u >> 16);
}

// ---------------------------------------------------------------- norms
__global__ __launch_bounds__(256) void vq_norms(const float* __restrict__ cb,
                                                float* __restrict__ norms) {
    int code = blockIdx.x * 4 + (threadIdx.x >> 6);
    int lane = threadIdx.x & 63;
    const float4* p = (const float4*)(cb + (size_t)code * DDIM);
    float4 a = p[lane];
    float4 b = p[lane + 64];
    float s = a.x * a.x + a.y * a.y + a.z * a.z + a.w * a.w +
              b.x * b.x + b.y * b.y + b.z * b.z + b.w * b.w;
#pragma unroll
    for (int m = 32; m >= 1; m >>= 1) s += __shfl_xor(s, m);
    if (lane == 0) norms[code] = s;
}

// ---------------------------------------------------------------- cb pack (ALL levels)
// Frag-major bf16 hi/lo per level: slot s covers code=tile*16+(lane&15),
// k = kc*32 + (lane>>4)*8 + j.  Wave B-load = 64 lanes x 16B contiguous.
__global__ __launch_bounds__(256) void vq_cbpack(const float* __restrict__ cbs,
                                                 ushort* __restrict__ pkHi,
                                                 ushort* __restrict__ pkLo) {
    int sg = blockIdx.x * 256 + threadIdx.x;   // 0..524287 (8 levels x 65536 slots)
    int lvl = sg >> 16;
    int s = sg & 65535;
    int tile = s >> 10;
    int kc = (s >> 6) & 15;
    int ln = s & 63;
    int code = tile * 16 + (ln & 15);
    int k0 = kc * 32 + (ln >> 4) * 8;
    const float* p = cbs + (size_t)lvl * CDN * DDIM + (size_t)code * DDIM + k0;
    float f[8];
    *(float4*)&f[0] = *(const float4*)p;
    *(float4*)&f[4] = *(const float4*)(p + 4);
    ushort h[8], l[8];
#pragma unroll
    for (int i = 0; i < 8; i++) {
        h[i] = f2bf(f[i]);
        float hf = __uint_as_float(((unsigned)h[i]) << 16);
        l[i] = f2bf(f[i] - hf);
    }
    *(short8*)(pkHi + (size_t)sg * 8) = *(short8*)h;
    *(short8*)(pkLo + (size_t)sg * 8) = *(short8*)l;
}

// ---------------------------------------------------------------- fused level (MFMA)
// 8-wave, spill-free schedule:
//  - __launch_bounds__(512, 2): 2nd arg behaves as min BLOCKS/CU (CUDA
//    semantics, measured: (512,4) -> 64-VGPR cap & spills).  2 blocks x 8
//    waves = 16 waves/CU -> 128-VGPR cap; LDS (75 KB) already limits to 2.
//  - codes split: h in {0,1} selects a ct-PAIR (ct = 2h+ctl); kc inner.
//    Live acc is acc[2][2][2] (32 VGPR); A loaded once per kc (4 ds_read per
//    24 MFMAs); B depth-1 ping-pong with parity == ctl (literal indices).
//  - top-3 indices held as PACKED 6-bit tile ids (one reg/slot) during the
//    loop (codes per lane share l15); unpacked to full codes after.
// A LDS layout: chunk c=k/8 of row r at  r*512 + ((c ^ (r&7))*8) ushorts.
__global__ __launch_bounds__(TPB, 2) void vq_level_mfma(
    const float* __restrict__ rsrc, const float* __restrict__ qsub,
    float* __restrict__ resid, float* __restrict__ quant,
    const float* __restrict__ cbq, const float* __restrict__ normq,
    const ushort* __restrict__ pkHi, const ushort* __restrict__ pkLo,
    float* __restrict__ idx_out, double* __restrict__ lossq,
    int* __restrict__ fbCnt, int* __restrict__ fbList, int q) {
    __shared__ ushort Ah[BR * 512];          // 32 KB
    __shared__ ushort Al[BR * 512];          // 32 KB
    __shared__ float s_nrm[CDN];             // 4 KB
    __shared__ float m_d1[NWAVE][BR], m_d2[NWAVE][BR], m_d3[NWAVE][BR];
    __shared__ int m_i1[NWAVE][BR], m_i2[NWAVE][BR];
    __shared__ int s_i1[BR], s_i2[BR], s_flag[BR];
    __shared__ double s_part[NWAVE];

    int tid = threadIdx.x;
    int lane = tid & 63;
    int l15 = lane & 15;
    int quad = lane >> 4;
    int cg = tid >> 6;      // wave = code group (0..7)
    int row0 = blockIdx.x * BR;

    for (int i = tid; i < CDN; i += TPB) s_nrm[i] = normq[i];

    // ---- stage full-K A: 2048 chunks of 8 floats
#pragma unroll
    for (int i = 0; i < 2048 / TPB; i++) {
        int flat = tid + TPB * i;       // 0..2047
        int row = flat >> 6;
        int c = flat & 63;
        size_t g = (size_t)(row0 + row) * DDIM + c * 8;
        float f[8];
        *(float4*)&f[0] = *(const float4*)(rsrc + g);
        *(float4*)&f[4] = *(const float4*)(rsrc + g + 4);
        if (qsub) {
            float4 w0 = *(const float4*)(qsub + g);
            float4 w1 = *(const float4*)(qsub + g + 4);
            f[0] -= w0.x; f[1] -= w0.y; f[2] -= w0.z; f[3] -= w0.w;
            f[4] -= w1.x; f[5] -= w1.y; f[6] -= w1.z; f[7] -= w1.w;
        }
        ushort h[8], l[8];
#pragma unroll
        for (int k = 0; k < 8; k++) {
            h[k] = f2bf(f[k]);
            float hf = __uint_as_float(((unsigned)h[k]) << 16);
            l[k] = f2bf(f[k] - hf);
        }
        int dst = row * 512 + ((c ^ (row & 7)) * 8);
        *(short8*)(Ah + dst) = *(short8*)h;
        *(short8*)(Al + dst) = *(short8*)l;
    }
    __syncthreads();
    // -------- no __syncthreads below until after the MFMA loop --------

    // per-lane top-3 per slot (rt*4+reg); indices packed: t12 = ti1 | ti2<<6
    float td1[8], td2[8], td3[8];
    int t12[8];
#pragma unroll
    for (int s = 0; s < 8; s++) { td1[s] = 3.4e38f; td2[s] = 3.4e38f; td3[s] = 3.4e38f; t12[s] = 0; }

    short8 aR[4];                       // A hi/lo for rows l15, l15+16 (current kc)
    short8 bhR[2][2], blR[2][2];        // B ping-pong, parity == ctl
    f32x4 acc[2][2][2];                 // [rt][ctl][j] -- 32 VGPR live
    int aswz = l15 & 7;                 // (16+l15)&7 == l15&7

    // wave cg covers code tiles ct*16 + cg*2 + j (j=0..1), ct = 2h + ctl
#define LOADB(ct, kc, P) { int base_ = (ct) * 131072 + cg * 16384 + (kc) * 512 + lane * 8; \
    bhR[P][0] = *(const short8*)(pkHi + base_); \
    blR[P][0] = *(const short8*)(pkLo + base_); \
    bhR[P][1] = *(const short8*)(pkHi + base_ + 8192); \
    blR[P][1] = *(const short8*)(pkLo + base_ + 8192); }

#define LOADA(kc) { int c0_ = ((kc) * 4 + quad) ^ aswz; \
    aR[0] = *(short8*)(Ah + l15 * 512 + c0_ * 8); \
    aR[1] = *(short8*)(Al + l15 * 512 + c0_ * 8); \
    aR[2] = *(short8*)(Ah + (16 + l15) * 512 + c0_ * 8); \
    aR[3] = *(short8*)(Al + (16 + l15) * 512 + c0_ * 8); }

    // 12 MFMAs for ctl=CT (literal): 3-split x 2 rt x 2 j
#define MSTEP(CT) { \
    _Pragma("unroll") for (int j = 0; j < 2; j++) { \
        acc[0][CT][j] = __builtin_amdgcn_mfma_f32_16x16x32_bf16(aR[0], bhR[CT][j], acc[0][CT][j], 0, 0, 0); \
        acc[0][CT][j] = __builtin_amdgcn_mfma_f32_16x16x32_bf16(aR[1], bhR[CT][j], acc[0][CT][j], 0, 0, 0); \
        acc[0][CT][j] = __builtin_amdgcn_mfma_f32_16x16x32_bf16(aR[0], blR[CT][j], acc[0][CT][j], 0, 0, 0); \
        acc[1][CT][j] = __builtin_amdgcn_mfma_f32_16x16x32_bf16(aR[2], bhR[CT][j], acc[1][CT][j], 0, 0, 0); \
        acc[1][CT][j] = __builtin_amdgcn_mfma_f32_16x16x32_bf16(aR[3], bhR[CT][j], acc[1][CT][j], 0, 0, 0); \
        acc[1][CT][j] = __builtin_amdgcn_mfma_f32_16x16x32_bf16(aR[2], blR[CT][j], acc[1][CT][j], 0, 0, 0); } }

    LOADB(0, 0, 0);                     // prologue: (ct=0, kc=0) into parity 0
#pragma unroll
    for (int h = 0; h < 2; h++) {
        int ct0 = 2 * h, ct1 = 2 * h + 1;
#pragma unroll
        for (int rt = 0; rt < 2; rt++)
#pragma unroll
            for (int c = 0; c < 2; c++)
#pragma unroll
                for (int j = 0; j < 2; j++) acc[rt][c][j] = (f32x4)0.0f;
#pragma unroll 2
        for (int kc = 0; kc < 16; kc++) {
            LOADB(ct1, kc, 1);          // B for ctl=1 of this kc (long lead)
            LOADA(kc);                  // A for both ctl steps
            MSTEP(0);
            int kn = (kc + 1) & 15;
            int cn = (kc == 15) ? ((ct1 + 1) & 3) : ct0;   // next half's ct0; h=1 end = dummy
            LOADB(cn, kn, 0);           // B for ctl=0 of next kc / next half
            MSTEP(1);
        }
        // top-3 selection for this ct-pair.  Candidate tiles ascend =>
        // strict '<' keeps the lowest index on exact ties, matching argmin.
#pragma unroll
        for (int c = 0; c < 2; c++)
#pragma unroll
            for (int jj = 0; jj < 2; jj++) {
                int tile = (2 * h + c) * 16 + cg * 2 + jj;     // 6-bit
                float nrm = s_nrm[tile * 16 + l15];
#pragma unroll
                for (int rt = 0; rt < 2; rt++)
#pragma unroll
                    for (int reg = 0; reg < 4; reg++) {
                        float v = nrm - 2.0f * acc[rt][c][jj][reg];
                        int s = rt * 4 + reg;
                        bool b1 = v < td1[s]; bool b2 = v < td2[s]; bool b3 = v < td3[s];
                        int pb1 = ((t12[s] & 63) << 6) | tile;   // ti2=ti1, ti1=tile
                        int pb2 = (tile << 6) | (t12[s] & 63);   // ti2=tile
                        td3[s] = b2 ? td2[s] : (b3 ? v : td3[s]);
                        t12[s] = b1 ? pb1 : (b2 ? pb2 : t12[s]);
                        td2[s] = b1 ? td1[s] : (b2 ? v : td2[s]);
                        td1[s] = b1 ? v : td1[s];
                    }
            }
    }
#undef LOADB
#undef LOADA
#undef MSTEP

    // unpack tile ids -> full codes (register pressure relaxed here)
    int ti1[8], ti2[8];
#pragma unroll
    for (int s = 0; s < 8; s++) {
        ti1[s] = (t12[s] & 63) * 16 + l15;
        ti2[s] = ((t12[s] >> 6) & 63) * 16 + l15;
    }

    // butterfly merge over 16 l15-lanes (quad preserved)
#pragma unroll
    for (int m = 1; m <= 8; m <<= 1) {
#pragma unroll
        for (int s = 0; s < 8; s++) {
            float o1 = __shfl_xor(td1[s], m); int oi1 = __shfl_xor(ti1[s], m);
            float o2 = __shfl_xor(td2[s], m); int oi2 = __shfl_xor(ti2[s], m);
            float o3 = __shfl_xor(td3[s], m);
            bool aw = (td1[s] < o1) || (td1[s] == o1 && ti1[s] < oi1);
            float w2 = aw ? td2[s] : o2; int wi2 = aw ? ti2[s] : oi2;
            float w3 = aw ? td3[s] : o3;
            float n1 = aw ? td1[s] : o1; int ni1 = aw ? ti1[s] : oi1;
            float p1 = aw ? o1 : td1[s]; int pi1 = aw ? oi1 : ti1[s];
            float p2 = aw ? o2 : td2[s];
            bool sw = (w2 < p1) || (w2 == p1 && wi2 < pi1);
            float n2 = sw ? w2 : p1; int ni2 = sw ? wi2 : pi1;
            float n3 = sw ? fminf(p1, w3) : fminf(w2, p2);
            td1[s] = n1; ti1[s] = ni1; td2[s] = n2; ti2[s] = ni2; td3[s] = n3;
        }
    }

    if (l15 == 0) {
#pragma unroll
        for (int s = 0; s < 8; s++) {
            int row = (s >> 2) * 16 + quad * 4 + (s & 3);
            m_d1[cg][row] = td1[s]; m_i1[cg][row] = ti1[s];
            m_d2[cg][row] = td2[s]; m_i2[cg][row] = ti2[s];
            m_d3[cg][row] = td3[s];
        }
    }
    __syncthreads();

    // 8-way cg merge + flagging (one thread per row)
    if (tid < BR) {
        int r = tid;
        float d1 = m_d1[0][r]; int i1 = m_i1[0][r];
        float d2 = m_d2[0][r]; int i2 = m_i2[0][r];
        float d3 = m_d3[0][r];
#pragma unroll
        for (int c = 1; c < NWAVE; c++) {
            float o1 = m_d1[c][r]; int oi1 = m_i1[c][r];
            float o2 = m_d2[c][r]; int oi2 = m_i2[c][r];
            float o3 = m_d3[c][r];
            bool aw = (d1 < o1) || (d1 == o1 && i1 < oi1);
            float w2 = aw ? d2 : o2; int wi2 = aw ? i2 : oi2;
            float w3 = aw ? d3 : o3;
            float n1 = aw ? d1 : o1; int ni1 = aw ? i1 : oi1;
            float p1 = aw ? o1 : d1; int pi1 = aw ? oi1 : i1;
            float p2 = aw ? o2 : d2;
            bool sw = (w2 < p1) || (w2 == p1 && wi2 < pi1);
            float n2 = sw ? w2 : p1; int ni2 = sw ? wi2 : pi1;
            float n3 = sw ? fminf(p1, w3) : fminf(w2, p2);
            d1 = n1; i1 = ni1; d2 = n2; i2 = ni2; d3 = n3;
        }
        int flag = 0;
        if (d3 - d1 < MARGIN) flag = 2;          // >=3 candidates: full fallback
        else if (d2 - d1 < MARGIN) flag = 1;     // 2 candidates: exact rescore
        s_i1[r] = i1; s_i2[r] = i2; s_flag[r] = flag;
        if (flag == 2) {
            int p = atomicAdd(fbCnt, 1);
            if (p < 32768) fbList[p] = row0 + r;
        }
    }
    __syncthreads();

    // exact fp32 rescore of 2-candidate rows (wave-cooperative)
    for (int r = cg; r < BR; r += NWAVE) {
        if (s_flag[r] != 1) continue;
        int i1 = s_i1[r], i2 = s_i2[r];
        size_t g = (size_t)(row0 + r) * DDIM + lane * 8;
        float rv[8];
        *(float4*)&rv[0] = *(const float4*)(rsrc + g);
        *(float4*)&rv[4] = *(const float4*)(rsrc + g + 4);
        if (qsub) {
            float4 w0 = *(const float4*)(qsub + g);
            float4 w1 = *(const float4*)(qsub + g + 4);
            rv[0] -= w0.x; rv[1] -= w0.y; rv[2] -= w0.z; rv[3] -= w0.w;
            rv[4] -= w1.x; rv[5] -= w1.y; rv[6] -= w1.z; rv[7] -= w1.w;
        }
        float c1[8], c2[8];
        *(float4*)&c1[0] = *(const float4*)(cbq + (size_t)i1 * DDIM + lane * 8);
        *(float4*)&c1[4] = *(const float4*)(cbq + (size_t)i1 * DDIM + lane * 8 + 4);
        *(float4*)&c2[0] = *(const float4*)(cbq + (size_t)i2 * DDIM + lane * 8);
        *(float4*)&c2[4] = *(const float4*)(cbq + (size_t)i2 * DDIM + lane * 8 + 4);
        float e1 = 0.0f, e2 = 0.0f;
#pragma unroll
        for (int i = 0; i < 8; i++) { e1 = fmaf(rv[i], c1[i], e1); e2 = fmaf(rv[i], c2[i], e2); }
#pragma unroll
        for (int m = 32; m >= 1; m >>= 1) { e1 += __shfl_xor(e1, m); e2 += __shfl_xor(e2, m); }
        float dd1 = s_nrm[i1] - 2.0f * e1;
        float dd2 = s_nrm[i2] - 2.0f * e2;
        bool take2 = (dd2 < dd1) || (dd2 == dd1 && i2 < i1);
        if (lane == 0) s_i1[r] = take2 ? i2 : i1;
    }
    __syncthreads();

    if (tid < BR) idx_out[(size_t)(row0 + tid) * QD + q] = (float)s_i1[tid];

    // update phase: resid_new = r - cb[idx]; loss += ||resid_new||^2 (skip fallback rows)
    double ls = 0.0;
#pragma unroll 4
    for (int it = 0; it < 4096 / TPB; it++) {
        int flat = tid + TPB * it;         // 0..4095 float4 chunks
        int row = flat >> 7;
        int c4 = (flat & 127) * 4;
        if (s_flag[row] == 2) continue;
        size_t g = (size_t)(row0 + row) * DDIM + c4;
        float4 r = *(const float4*)(rsrc + g);
        if (qsub) {
            float4 w = *(const float4*)(qsub + g);
            r.x -= w.x; r.y -= w.y; r.z -= w.z; r.w -= w.w;
        }
        float4 cv = *(const float4*)(cbq + (size_t)s_i1[row] * DDIM + c4);
        float4 nr;
        nr.x = r.x - cv.x; nr.y = r.y - cv.y; nr.z = r.z - cv.z; nr.w = r.w - cv.w;
        if (resid) {
            *(float4*)(resid + g) = nr;
        } else {
            float4 qo = *(float4*)(quant + g);
            qo.x += cv.x; qo.y += cv.y; qo.z += cv.z; qo.w += cv.w;
            *(float4*)(quant + g) = qo;
        }
        ls += (double)nr.x * nr.x + (double)nr.y * nr.y +
              (double)nr.z * nr.z + (double)nr.w * nr.w;
    }
#pragma unroll
    for (int m = 32; m >= 1; m >>= 1) ls += __shfl_down(ls, m);
    if ((tid & 63) == 0) s_part[tid >> 6] = ls;
    __syncthreads();
    if (tid == 0) {
        double t = 0.0;
#pragma unroll
        for (int i = 0; i < NWAVE; i++) t += s_part[i];
        atomicAdd(lossq, t);
    }
}

// ---------------------------------------------------------------- full-scan fallback (rare rows)
__global__ __launch_bounds__(256) void vq_fallback(
    const float* __restrict__ rsrc, const float* __restrict__ qsub,
    float* __restrict__ resid, float* __restrict__ quant,
    const float* __restrict__ cbq, const float* __restrict__ normq,
    float* __restrict__ idx_out, double* __restrict__ lossq,
    const int* __restrict__ fbCnt, const int* __restrict__ fbList, int q) {
    __shared__ float r_s[DDIM];
    __shared__ unsigned long long s_best;
    int tid = threadIdx.x;
    int n = *fbCnt; if (n > 32768) n = 32768;
    for (int w = blockIdx.x; w < n; w += gridDim.x) {
        int row = fbList[w];
        if (tid == 0) s_best = ~0ull;
        if (tid < 128) {
            size_t g = (size_t)row * DDIM + tid * 4;
            float4 v = *(const float4*)(rsrc + g);
            if (qsub) {
                float4 x = *(const float4*)(qsub + g);
                v.x -= x.x; v.y -= x.y; v.z -= x.z; v.w -= x.w;
            }
            *(float4*)&r_s[tid * 4] = v;
        }
        __syncthreads();
#pragma unroll
        for (int cc = 0; cc < 4; cc++) {
            int c = tid + 256 * cc;
            float dot = 0.0f;
            for (int k4 = 0; k4 < 128; k4++) {
                float4 cv = *(const float4*)(cbq + (size_t)c * DDIM + k4 * 4);
                float4 rv = *(const float4*)&r_s[k4 * 4];
                dot = fmaf(cv.x, rv.x, dot); dot = fmaf(cv.y, rv.y, dot);
                dot = fmaf(cv.z, rv.z, dot); dot = fmaf(cv.w, rv.w, dot);
            }
            float dist = normq[c] - 2.0f * dot;
            unsigned b = __float_as_uint(dist);
            b = (b & 0x80000000u) ? ~b : (b | 0x80000000u);
            unsigned long long key = (((unsigned long long)b) << 32) | (unsigned)c;
            atomicMin(&s_best, key);
        }
        __syncthreads();
        int idx = (int)(s_best & 0xffffffffull);
        if (tid == 0) idx_out[(size_t)row * QD + q] = (float)idx;
        double ls = 0.0;
        if (tid < 128) {
            size_t g = (size_t)row * DDIM + tid * 4;
            float4 r = *(const float4*)&r_s[tid * 4];
            float4 cv = *(const float4*)(cbq + (size_t)idx * DDIM + tid * 4);
            float4 nr;
            nr.x = r.x - cv.x; nr.y = r.y - cv.y; nr.z = r.z - cv.z; nr.w = r.w - cv.w;
            if (resid) {
                *(float4*)(resid + g) = nr;
            } else {
                float4 qo = *(float4*)(quant + g);
                qo.x += cv.x; qo.y += cv.y; qo.z += cv.z; qo.w += cv.w;
                *(float4*)(quant + g) = qo;
            }
            ls = (double)nr.x * nr.x + (double)nr.y * nr.y +
                 (double)nr.z * nr.z + (double)nr.w * nr.w;
        }
#pragma unroll
        for (int m = 32; m >= 1; m >>= 1) ls += __shfl_down(ls, m);
        if ((tid & 63) == 0 && ls != 0.0) atomicAdd(lossq, ls);
        __syncthreads();
    }
}

// ---------------------------------------------------------------- quant = x - resid_final
__global__ __launch_bounds__(256) void vq_quant_final(const float* __restrict__ x,
                                                      const float* __restrict__ resid,
                                                      float* __restrict__ quant) {
    size_t i = ((size_t)blockIdx.x * 256 + threadIdx.x) * 4;
    float4 xv = *(const float4*)(x + i);
    float4 rv = *(const float4*)(resid + i);
    float4 o;
    o.x = xv.x - rv.x; o.y = xv.y - rv.y; o.z = xv.z - rv.z; o.w = xv.w - rv.w;
    *(float4*)(quant + i) = o;
}

// ---------------------------------------------------------------- finalize losses
__global__ void vq_loss_final(const double* __restrict__ lossws, float* __restrict__ out) {
    int i = threadIdx.x;
    if (i < QD) out[i] = (float)(lossws[i] * (1.0 / (double)((size_t)ROWS * DDIM)));
}

// ---------------------------------------------------------------- launch
extern "C" void kernel_launch(void* const* d_in, const int* in_sizes, int n_in,
                              void* d_out, int out_size, void* d_ws, size_t ws_size,
                              hipStream_t stream) {
    const float* x = (const float*)d_in[0];
    const float* cbs = (const float*)d_in[1];
    float* out = (float*)d_out;
    float* quant = out;
    float* idxo = out + IDX_OFF;
    float* losso = out + LOSS_OFF;

    char* ws = (char*)d_ws;
    double* lossws = (double*)(ws + WS_LOSS);
    int* fbCnt = (int*)(ws + WS_FBCNT);
    int* fbList = (int*)(ws + WS_FBLIST);
    float* norms = (float*)(ws + WS_NORMS);
    ushort* pkHi = (ushort*)(ws + WS_PKHI);
    ushort* pkLo = (ushort*)(ws + WS_PKLO);
    float* resid = (ws_size >= (size_t)WS_RESID + (size_t)QUANT_ELEMS * 4)
                       ? (float*)(ws + WS_RESID) : nullptr;

    hipMemsetAsync(d_ws, 0, 128, stream);
    if (!resid) hipMemsetAsync(d_out, 0, (size_t)out_size * 4, stream);

    vq_norms<<<QD * CDN / 4, 256, 0, stream>>>(cbs, norms);
    vq_cbpack<<<QD * 256, 256, 0, stream>>>(cbs, pkHi, pkLo);   // all levels once

    for (int q = 0; q < QD; q++) {
        const float* cbq = cbs + (size_t)q * CDN * DDIM;
        const float* nq = norms + (size_t)q * CDN;
        const ushort* pH = pkHi + (size_t)q * CDN * DDIM;
        const ushort* pL = pkLo + (size_t)q * CDN * DDIM;
        const float* rsrc;
        const float* qsubA;
        if (resid) {
            rsrc = (q == 0) ? x : resid;
            qsubA = nullptr;
        } else {
            rsrc = x;
            qsubA = quant;
        }
        vq_level_mfma<<<ROWS / BR, TPB, 0, stream>>>(
            rsrc, qsubA, resid, quant, cbq, nq, pH, pL,
            idxo, lossws + q, fbCnt + q, fbList, q);
        vq_fallback<<<128, 256, 0, stream>>>(
            rsrc, qsubA, resid, quant, cbq, nq, idxo, lossws + q,
            fbCnt + q, fbList, q);
    }
    if (resid) {
        vq_quant_final<<<QUANT_ELEMS / 1024, 256, 0, stream>>>(x, resid, quant);
    }
    vq_loss_final<<<1, 64, 0, stream>>>(lossws, losso);
}

// Round 4
// 2197.302 us; speedup vs baseline: 1.1013x; 1.1013x over previous
//
#include <hip/hip_runtime.h>

// Problem constants (fixed by the reference)
#define BD 8
#define SD 4096
#define DDIM 512
#define QD 8
#define CDN 1024
#define ROWS (BD * SD)              // 32768
#define QUANT_ELEMS (ROWS * DDIM)   // 16777216
#define IDX_OFF QUANT_ELEMS
#define LOSS_OFF (QUANT_ELEMS + ROWS * QD)

#define TPB 256
#define NWAVE (TPB / 64)            // 4 waves/block
#define BR 32                       // rows per block
// 3-MFMA split (ah*bh + al*bh + ah*bl): max dist error ~2e-3 << MARGIN/2.
#define MARGIN 0.25f

// ws layout (bytes)
#define WS_LOSS 0                   // 8 doubles
#define WS_FBCNT 64                 // 8 ints
#define WS_FBLIST 4096              // 32768 ints (128 KB)
#define WS_NORMS 0x40000            // 32 KB
#define WS_PKHI 0x100000            // 8 MB (all levels)
#define WS_PKLO 0x900000            // 8 MB
#define WS_RESID 0x1100000          // 64 MB

typedef __attribute__((ext_vector_type(8))) short short8;
typedef __attribute__((ext_vector_type(4))) float f32x4;

__device__ __forceinline__ ushort f2bf(float x) {
    unsigned u = __float_as_uint(x);
    u += 0x7fff + ((u >> 16) & 1);          // RTNE
    return (ushort)(u >> 16);
}

// ---------------------------------------------------------------- norms
__global__ __launch_bounds__(256) void vq_norms(const float* __restrict__ cb,
                                                float* __restrict__ norms) {
    int code = blockIdx.x * 4 + (threadIdx.x >> 6);
    int lane = threadIdx.x & 63;
    const float4* p = (const float4*)(cb + (size_t)code * DDIM);
    float4 a = p[lane];
    float4 b = p[lane + 64];
    float s = a.x * a.x + a.y * a.y + a.z * a.z + a.w * a.w +
              b.x * b.x + b.y * b.y + b.z * b.z + b.w * b.w;
#pragma unroll
    for (int m = 32; m >= 1; m >>= 1) s += __shfl_xor(s, m);
    if (lane == 0) norms[code] = s;
}

// ---------------------------------------------------------------- cb pack (ALL levels)
// Frag-major bf16 hi/lo per level: slot s covers code=tile*16+(lane&15),
// k = kc*32 + (lane>>4)*8 + j.  Wave B-load = 64 lanes x 16B contiguous.
__global__ __launch_bounds__(256) void vq_cbpack(const float* __restrict__ cbs,
                                                 ushort* __restrict__ pkHi,
                                                 ushort* __restrict__ pkLo) {
    int sg = blockIdx.x * 256 + threadIdx.x;   // 0..524287 (8 levels x 65536 slots)
    int lvl = sg >> 16;
    int s = sg & 65535;
    int tile = s >> 10;
    int kc = (s >> 6) & 15;
    int ln = s & 63;
    int code = tile * 16 + (ln & 15);
    int k0 = kc * 32 + (ln >> 4) * 8;
    const float* p = cbs + (size_t)lvl * CDN * DDIM + (size_t)code * DDIM + k0;
    float f[8];
    *(float4*)&f[0] = *(const float4*)p;
    *(float4*)&f[4] = *(const float4*)(p + 4);
    ushort h[8], l[8];
#pragma unroll
    for (int i = 0; i < 8; i++) {
        h[i] = f2bf(f[i]);
        float hf = __uint_as_float(((unsigned)h[i]) << 16);
        l[i] = f2bf(f[i] - hf);
    }
    *(short8*)(pkHi + (size_t)sg * 8) = *(short8*)h;
    *(short8*)(pkLo + (size_t)sg * 8) = *(short8*)l;
}

// ---------------------------------------------------------------- fused level (MFMA)
// 4-wave (TPB=256), 2 blocks/CU (LDS-limited), 2 waves/SIMD -> 256-VGPR budget.
// __launch_bounds__(256,2): both launch-bounds interpretations agree on a
// 256-VGPR cap here (measured decoder: cap = 512/waves_per_SIMD).
// Schedule (deep-pipelined, barrier-free after 1 staging barrier):
//  - ct-PAIR outer h in {0,1} (ct = 2h+ctl); kc inner.  A-LDS traffic halved
//    vs the g-loop (A loaded once per kc, serves 48 MFMAs).
//  - acc[2 rt][2 ctl][4 j] = 64 VGPR, wave cg covers tiles ct*16+cg*4+j.
//  - A ping-pong (aR[2][4]): A(kc+1) issued a full 48-MFMA step ahead.
//  - B two fixed buffers: B1(ct1,kc) issued 24 MFMAs before use (over
//    MSTEP0); B0(ct0,kc+1) issued 24 MFMAs before use (over MSTEP1).
//  - top-3 selection per h over the 64 accumulated dots; indices packed as
//    6-bit tile ids (t12), unpacked after the loop.
// Live regs ~ acc64 + B64 + A32 + td24 + t12 8 + addr ~ 200 < 256: no spill.
// A LDS layout: chunk c=k/8 of row r at  r*512 + ((c ^ (r&7))*8) ushorts.
__global__ __launch_bounds__(TPB, 2) void vq_level_mfma(
    const float* __restrict__ rsrc, const float* __restrict__ qsub,
    float* __restrict__ resid, float* __restrict__ quant,
    const float* __restrict__ cbq, const float* __restrict__ normq,
    const ushort* __restrict__ pkHi, const ushort* __restrict__ pkLo,
    float* __restrict__ idx_out, double* __restrict__ lossq,
    int* __restrict__ fbCnt, int* __restrict__ fbList, int q) {
    __shared__ ushort Ah[BR * 512];          // 32 KB
    __shared__ ushort Al[BR * 512];          // 32 KB
    __shared__ float s_nrm[CDN];             // 4 KB
    __shared__ float m_d1[NWAVE][BR], m_d2[NWAVE][BR], m_d3[NWAVE][BR];
    __shared__ int m_i1[NWAVE][BR], m_i2[NWAVE][BR];
    __shared__ int s_i1[BR], s_i2[BR], s_flag[BR];
    __shared__ double s_part[NWAVE];

    int tid = threadIdx.x;
    int lane = tid & 63;
    int l15 = lane & 15;
    int quad = lane >> 4;
    int cg = tid >> 6;      // wave = code group (0..3)
    int row0 = blockIdx.x * BR;

    for (int i = tid; i < CDN; i += TPB) s_nrm[i] = normq[i];

    // ---- stage full-K A: 2048 chunks of 8 floats
#pragma unroll
    for (int i = 0; i < 2048 / TPB; i++) {
        int flat = tid + TPB * i;       // 0..2047
        int row = flat >> 6;
        int c = flat & 63;
        size_t g = (size_t)(row0 + row) * DDIM + c * 8;
        float f[8];
        *(float4*)&f[0] = *(const float4*)(rsrc + g);
        *(float4*)&f[4] = *(const float4*)(rsrc + g + 4);
        if (qsub) {
            float4 w0 = *(const float4*)(qsub + g);
            float4 w1 = *(const float4*)(qsub + g + 4);
            f[0] -= w0.x; f[1] -= w0.y; f[2] -= w0.z; f[3] -= w0.w;
            f[4] -= w1.x; f[5] -= w1.y; f[6] -= w1.z; f[7] -= w1.w;
        }
        ushort h[8], l[8];
#pragma unroll
        for (int k = 0; k < 8; k++) {
            h[k] = f2bf(f[k]);
            float hf = __uint_as_float(((unsigned)h[k]) << 16);
            l[k] = f2bf(f[k] - hf);
        }
        int dst = row * 512 + ((c ^ (row & 7)) * 8);
        *(short8*)(Ah + dst) = *(short8*)h;
        *(short8*)(Al + dst) = *(short8*)l;
    }
    __syncthreads();
    // -------- no __syncthreads below until after the MFMA loop --------

    // per-lane top-3 per slot (rt*4+reg); indices packed: t12 = ti1 | ti2<<6
    float td1[8], td2[8], td3[8];
    int t12[8];
#pragma unroll
    for (int s = 0; s < 8; s++) { td1[s] = 3.4e38f; td2[s] = 3.4e38f; td3[s] = 3.4e38f; t12[s] = 0; }

    short8 aR[2][4];                    // A ping-pong: hi/lo rows l15, l15+16
    short8 bh0[4], bl0[4];              // B buffer ctl=0 (current kc)
    short8 bh1[4], bl1[4];              // B buffer ctl=1 (current kc)
    f32x4 acc[2][2][4];                 // [rt][ctl][j] -- 64 VGPR live
    int aswz = l15 & 7;                 // (16+l15)&7 == l15&7

    // wave cg covers code tiles ct*16 + cg*4 + j (j=0..3), ct = 2h + ctl
#define LOADB0(ct, kc) { int base_ = (ct) * 131072 + cg * 32768 + (kc) * 512 + lane * 8; \
    _Pragma("unroll") for (int j = 0; j < 4; j++) { \
        bh0[j] = *(const short8*)(pkHi + base_ + j * 8192); \
        bl0[j] = *(const short8*)(pkLo + base_ + j * 8192); } }

#define LOADB1(ct, kc) { int base_ = (ct) * 131072 + cg * 32768 + (kc) * 512 + lane * 8; \
    _Pragma("unroll") for (int j = 0; j < 4; j++) { \
        bh1[j] = *(const short8*)(pkHi + base_ + j * 8192); \
        bl1[j] = *(const short8*)(pkLo + base_ + j * 8192); } }

#define LOADA(kc, P) { int c0_ = ((kc) * 4 + quad) ^ aswz; \
    aR[P][0] = *(short8*)(Ah + l15 * 512 + c0_ * 8); \
    aR[P][1] = *(short8*)(Al + l15 * 512 + c0_ * 8); \
    aR[P][2] = *(short8*)(Ah + (16 + l15) * 512 + c0_ * 8); \
    aR[P][3] = *(short8*)(Al + (16 + l15) * 512 + c0_ * 8); }

    // 24 MFMAs for ctl=CT using B buffer CT and A parity PA (all literal)
#define MSTEP(CT, PA, BH, BL) { \
    _Pragma("unroll") for (int j = 0; j < 4; j++) { \
        acc[0][CT][j] = __builtin_amdgcn_mfma_f32_16x16x32_bf16(aR[PA][0], BH[j], acc[0][CT][j], 0, 0, 0); \
        acc[0][CT][j] = __builtin_amdgcn_mfma_f32_16x16x32_bf16(aR[PA][1], BH[j], acc[0][CT][j], 0, 0, 0); \
        acc[0][CT][j] = __builtin_amdgcn_mfma_f32_16x16x32_bf16(aR[PA][0], BL[j], acc[0][CT][j], 0, 0, 0); \
        acc[1][CT][j] = __builtin_amdgcn_mfma_f32_16x16x32_bf16(aR[PA][2], BH[j], acc[1][CT][j], 0, 0, 0); \
        acc[1][CT][j] = __builtin_amdgcn_mfma_f32_16x16x32_bf16(aR[PA][3], BH[j], acc[1][CT][j], 0, 0, 0); \
        acc[1][CT][j] = __builtin_amdgcn_mfma_f32_16x16x32_bf16(aR[PA][2], BL[j], acc[1][CT][j], 0, 0, 0); } }

    // one kc step: B1 issued 24 MFMAs ahead of use; A(kc+1) 48 ahead;
    // B0(next) issued 24 ahead of its use in the next step's MSTEP0.
#define STEP(kc, PA, ct0, ct1) { \
    LOADB1(ct1, kc); \
    LOADA(((kc) + 1) & 15, 1 - (PA)); \
    MSTEP(0, PA, bh0, bl0); \
    { int cn_ = ((kc) < 15) ? (ct0) : (((ct0) + 2) & 3); \
      int kn_ = ((kc) + 1) & 15; \
      LOADB0(cn_, kn_); } \
    MSTEP(1, PA, bh1, bl1); }

    LOADB0(0, 0);                       // prologue: B(ct=0, kc=0)
    LOADA(0, 0);                        // prologue: A(kc=0) parity 0
#pragma unroll
    for (int h = 0; h < 2; h++) {
        int ct0 = 2 * h, ct1 = 2 * h + 1;
#pragma unroll
        for (int rt = 0; rt < 2; rt++)
#pragma unroll
            for (int c = 0; c < 2; c++)
#pragma unroll
                for (int j = 0; j < 4; j++) acc[rt][c][j] = (f32x4)0.0f;
#pragma unroll 1
        for (int kc2 = 0; kc2 < 8; kc2++) {
            STEP(2 * kc2, 0, ct0, ct1);
            STEP(2 * kc2 + 1, 1, ct0, ct1);
        }
        // top-3 selection for this ct-pair.  Candidate tiles ascend =>
        // strict '<' keeps the lowest index on exact ties, matching argmin.
#pragma unroll
        for (int c = 0; c < 2; c++)
#pragma unroll
            for (int jj = 0; jj < 4; jj++) {
                int tile = (2 * h + c) * 16 + cg * 4 + jj;     // 6-bit
                float nrm = s_nrm[tile * 16 + l15];
#pragma unroll
                for (int rt = 0; rt < 2; rt++)
#pragma unroll
                    for (int reg = 0; reg < 4; reg++) {
                        float v = nrm - 2.0f * acc[rt][c][jj][reg];
                        int s = rt * 4 + reg;
                        bool b1 = v < td1[s]; bool b2 = v < td2[s]; bool b3 = v < td3[s];
                        int pb1 = ((t12[s] & 63) << 6) | tile;   // ti2=ti1, ti1=tile
                        int pb2 = (tile << 6) | (t12[s] & 63);   // ti2=tile
                        td3[s] = b2 ? td2[s] : (b3 ? v : td3[s]);
                        t12[s] = b1 ? pb1 : (b2 ? pb2 : t12[s]);
                        td2[s] = b1 ? td1[s] : (b2 ? v : td2[s]);
                        td1[s] = b1 ? v : td1[s];
                    }
            }
    }
#undef LOADB0
#undef LOADB1
#undef LOADA
#undef MSTEP
#undef STEP

    // unpack tile ids -> full codes (register pressure relaxed here)
    int ti1[8], ti2[8];
#pragma unroll
    for (int s = 0; s < 8; s++) {
        ti1[s] = (t12[s] & 63) * 16 + l15;
        ti2[s] = ((t12[s] >> 6) & 63) * 16 + l15;
    }

    // butterfly merge over 16 l15-lanes (quad preserved)
#pragma unroll
    for (int m = 1; m <= 8; m <<= 1) {
#pragma unroll
        for (int s = 0; s < 8; s++) {
            float o1 = __shfl_xor(td1[s], m); int oi1 = __shfl_xor(ti1[s], m);
            float o2 = __shfl_xor(td2[s], m); int oi2 = __shfl_xor(ti2[s], m);
            float o3 = __shfl_xor(td3[s], m);
            bool aw = (td1[s] < o1) || (td1[s] == o1 && ti1[s] < oi1);
            float w2 = aw ? td2[s] : o2; int wi2 = aw ? ti2[s] : oi2;
            float w3 = aw ? td3[s] : o3;
            float n1 = aw ? td1[s] : o1; int ni1 = aw ? ti1[s] : oi1;
            float p1 = aw ? o1 : td1[s]; int pi1 = aw ? oi1 : ti1[s];
            float p2 = aw ? o2 : td2[s];
            bool sw = (w2 < p1) || (w2 == p1 && wi2 < pi1);
            float n2 = sw ? w2 : p1; int ni2 = sw ? wi2 : pi1;
            float n3 = sw ? fminf(p1, w3) : fminf(w2, p2);
            td1[s] = n1; ti1[s] = ni1; td2[s] = n2; ti2[s] = ni2; td3[s] = n3;
        }
    }

    if (l15 == 0) {
#pragma unroll
        for (int s = 0; s < 8; s++) {
            int row = (s >> 2) * 16 + quad * 4 + (s & 3);
            m_d1[cg][row] = td1[s]; m_i1[cg][row] = ti1[s];
            m_d2[cg][row] = td2[s]; m_i2[cg][row] = ti2[s];
            m_d3[cg][row] = td3[s];
        }
    }
    __syncthreads();

    // 4-way cg merge + flagging (one thread per row)
    if (tid < BR) {
        int r = tid;
        float d1 = m_d1[0][r]; int i1 = m_i1[0][r];
        float d2 = m_d2[0][r]; int i2 = m_i2[0][r];
        float d3 = m_d3[0][r];
#pragma unroll
        for (int c = 1; c < NWAVE; c++) {
            float o1 = m_d1[c][r]; int oi1 = m_i1[c][r];
            float o2 = m_d2[c][r]; int oi2 = m_i2[c][r];
            float o3 = m_d3[c][r];
            bool aw = (d1 < o1) || (d1 == o1 && i1 < oi1);
            float w2 = aw ? d2 : o2; int wi2 = aw ? i2 : oi2;
            float w3 = aw ? d3 : o3;
            float n1 = aw ? d1 : o1; int ni1 = aw ? i1 : oi1;
            float p1 = aw ? o1 : d1; int pi1 = aw ? oi1 : i1;
            float p2 = aw ? o2 : d2;
            bool sw = (w2 < p1) || (w2 == p1 && wi2 < pi1);
            float n2 = sw ? w2 : p1; int ni2 = sw ? wi2 : pi1;
            float n3 = sw ? fminf(p1, w3) : fminf(w2, p2);
            d1 = n1; i1 = ni1; d2 = n2; i2 = ni2; d3 = n3;
        }
        int flag = 0;
        if (d3 - d1 < MARGIN) flag = 2;          // >=3 candidates: full fallback
        else if (d2 - d1 < MARGIN) flag = 1;     // 2 candidates: exact rescore
        s_i1[r] = i1; s_i2[r] = i2; s_flag[r] = flag;
        if (flag == 2) {
            int p = atomicAdd(fbCnt, 1);
            if (p < 32768) fbList[p] = row0 + r;
        }
    }
    __syncthreads();

    // exact fp32 rescore of 2-candidate rows (wave-cooperative)
    for (int r = cg; r < BR; r += NWAVE) {
        if (s_flag[r] != 1) continue;
        int i1 = s_i1[r], i2 = s_i2[r];
        size_t g = (size_t)(row0 + r) * DDIM + lane * 8;
        float rv[8];
        *(float4*)&rv[0] = *(const float4*)(rsrc + g);
        *(float4*)&rv[4] = *(const float4*)(rsrc + g + 4);
        if (qsub) {
            float4 w0 = *(const float4*)(qsub + g);
            float4 w1 = *(const float4*)(qsub + g + 4);
            rv[0] -= w0.x; rv[1] -= w0.y; rv[2] -= w0.z; rv[3] -= w0.w;
            rv[4] -= w1.x; rv[5] -= w1.y; rv[6] -= w1.z; rv[7] -= w1.w;
        }
        float c1[8], c2[8];
        *(float4*)&c1[0] = *(const float4*)(cbq + (size_t)i1 * DDIM + lane * 8);
        *(float4*)&c1[4] = *(const float4*)(cbq + (size_t)i1 * DDIM + lane * 8 + 4);
        *(float4*)&c2[0] = *(const float4*)(cbq + (size_t)i2 * DDIM + lane * 8);
        *(float4*)&c2[4] = *(const float4*)(cbq + (size_t)i2 * DDIM + lane * 8 + 4);
        float e1 = 0.0f, e2 = 0.0f;
#pragma unroll
        for (int i = 0; i < 8; i++) { e1 = fmaf(rv[i], c1[i], e1); e2 = fmaf(rv[i], c2[i], e2); }
#pragma unroll
        for (int m = 32; m >= 1; m >>= 1) { e1 += __shfl_xor(e1, m); e2 += __shfl_xor(e2, m); }
        float dd1 = s_nrm[i1] - 2.0f * e1;
        float dd2 = s_nrm[i2] - 2.0f * e2;
        bool take2 = (dd2 < dd1) || (dd2 == dd1 && i2 < i1);
        if (lane == 0) s_i1[r] = take2 ? i2 : i1;
    }
    __syncthreads();

    if (tid < BR) idx_out[(size_t)(row0 + tid) * QD + q] = (float)s_i1[tid];

    // update phase: resid_new = r - cb[idx]; loss += ||resid_new||^2 (skip fallback rows)
    double ls = 0.0;
#pragma unroll 4
    for (int it = 0; it < 4096 / TPB; it++) {
        int flat = tid + TPB * it;         // 0..4095 float4 chunks
        int row = flat >> 7;
        int c4 = (flat & 127) * 4;
        if (s_flag[row] == 2) continue;
        size_t g = (size_t)(row0 + row) * DDIM + c4;
        float4 r = *(const float4*)(rsrc + g);
        if (qsub) {
            float4 w = *(const float4*)(qsub + g);
            r.x -= w.x; r.y -= w.y; r.z -= w.z; r.w -= w.w;
        }
        float4 cv = *(const float4*)(cbq + (size_t)s_i1[row] * DDIM + c4);
        float4 nr;
        nr.x = r.x - cv.x; nr.y = r.y - cv.y; nr.z = r.z - cv.z; nr.w = r.w - cv.w;
        if (resid) {
            *(float4*)(resid + g) = nr;
        } else {
            float4 qo = *(float4*)(quant + g);
            qo.x += cv.x; qo.y += cv.y; qo.z += cv.z; qo.w += cv.w;
            *(float4*)(quant + g) = qo;
        }
        ls += (double)nr.x * nr.x + (double)nr.y * nr.y +
              (double)nr.z * nr.z + (double)nr.w * nr.w;
    }
#pragma unroll
    for (int m = 32; m >= 1; m >>= 1) ls += __shfl_down(ls, m);
    if ((tid & 63) == 0) s_part[tid >> 6] = ls;
    __syncthreads();
    if (tid == 0) {
        double t = 0.0;
#pragma unroll
        for (int i = 0; i < NWAVE; i++) t += s_part[i];
        atomicAdd(lossq, t);
    }
}

// ---------------------------------------------------------------- full-scan fallback (rare rows)
__global__ __launch_bounds__(256) void vq_fallback(
    const float* __restrict__ rsrc, const float* __restrict__ qsub,
    float* __restrict__ resid, float* __restrict__ quant,
    const float* __restrict__ cbq, const float* __restrict__ normq,
    float* __restrict__ idx_out, double* __restrict__ lossq,
    const int* __restrict__ fbCnt, const int* __restrict__ fbList, int q) {
    __shared__ float r_s[DDIM];
    __shared__ unsigned long long s_best;
    int tid = threadIdx.x;
    int n = *fbCnt; if (n > 32768) n = 32768;
    for (int w = blockIdx.x; w < n; w += gridDim.x) {
        int row = fbList[w];
        if (tid == 0) s_best = ~0ull;
        if (tid < 128) {
            size_t g = (size_t)row * DDIM + tid * 4;
            float4 v = *(const float4*)(rsrc + g);
            if (qsub) {
                float4 x = *(const float4*)(qsub + g);
                v.x -= x.x; v.y -= x.y; v.z -= x.z; v.w -= x.w;
            }
            *(float4*)&r_s[tid * 4] = v;
        }
        __syncthreads();
#pragma unroll
        for (int cc = 0; cc < 4; cc++) {
            int c = tid + 256 * cc;
            float dot = 0.0f;
            for (int k4 = 0; k4 < 128; k4++) {
                float4 cv = *(const float4*)(cbq + (size_t)c * DDIM + k4 * 4);
                float4 rv = *(const float4*)&r_s[k4 * 4];
                dot = fmaf(cv.x, rv.x, dot); dot = fmaf(cv.y, rv.y, dot);
                dot = fmaf(cv.z, rv.z, dot); dot = fmaf(cv.w, rv.w, dot);
            }
            float dist = normq[c] - 2.0f * dot;
            unsigned b = __float_as_uint(dist);
            b = (b & 0x80000000u) ? ~b : (b | 0x80000000u);
            unsigned long long key = (((unsigned long long)b) << 32) | (unsigned)c;
            atomicMin(&s_best, key);
        }
        __syncthreads();
        int idx = (int)(s_best & 0xffffffffull);
        if (tid == 0) idx_out[(size_t)row * QD + q] = (float)idx;
        double ls = 0.0;
        if (tid < 128) {
            size_t g = (size_t)row * DDIM + tid * 4;
            float4 r = *(const float4*)&r_s[tid * 4];
            float4 cv = *(const float4*)(cbq + (size_t)idx * DDIM + tid * 4);
            float4 nr;
            nr.x = r.x - cv.x; nr.y = r.y - cv.y; nr.z = r.z - cv.z; nr.w = r.w - cv.w;
            if (resid) {
                *(float4*)(resid + g) = nr;
            } else {
                float4 qo = *(float4*)(quant + g);
                qo.x += cv.x; qo.y += cv.y; qo.z += cv.z; qo.w += cv.w;
                *(float4*)(quant + g) = qo;
            }
            ls = (double)nr.x * nr.x + (double)nr.y * nr.y +
                 (double)nr.z * nr.z + (double)nr.w * nr.w;
        }
#pragma unroll
        for (int m = 32; m >= 1; m >>= 1) ls += __shfl_down(ls, m);
        if ((tid & 63) == 0 && ls != 0.0) atomicAdd(lossq, ls);
        __syncthreads();
    }
}

// ---------------------------------------------------------------- quant = x - resid_final
__global__ __launch_bounds__(256) void vq_quant_final(const float* __restrict__ x,
                                                      const float* __restrict__ resid,
                                                      float* __restrict__ quant) {
    size_t i = ((size_t)blockIdx.x * 256 + threadIdx.x) * 4;
    float4 xv = *(const float4*)(x + i);
    float4 rv = *(const float4*)(resid + i);
    float4 o;
    o.x = xv.x - rv.x; o.y = xv.y - rv.y; o.z = xv.z - rv.z; o.w = xv.w - rv.w;
    *(float4*)(quant + i) = o;
}

// ---------------------------------------------------------------- finalize losses
__global__ void vq_loss_final(const double* __restrict__ lossws, float* __restrict__ out) {
    int i = threadIdx.x;
    if (i < QD) out[i] = (float)(lossws[i] * (1.0 / (double)((size_t)ROWS * DDIM)));
}

// ---------------------------------------------------------------- launch
extern "C" void kernel_launch(void* const* d_in, const int* in_sizes, int n_in,
                              void* d_out, int out_size, void* d_ws, size_t ws_size,
                              hipStream_t stream) {
    const float* x = (const float*)d_in[0];
    const float* cbs = (const float*)d_in[1];
    float* out = (float*)d_out;
    float* quant = out;
    float* idxo = out + IDX_OFF;
    float* losso = out + LOSS_OFF;

    char* ws = (char*)d_ws;
    double* lossws = (double*)(ws + WS_LOSS);
    int* fbCnt = (int*)(ws + WS_FBCNT);
    int* fbList = (int*)(ws + WS_FBLIST);
    float* norms = (float*)(ws + WS_NORMS);
    ushort* pkHi = (ushort*)(ws + WS_PKHI);
    ushort* pkLo = (ushort*)(ws + WS_PKLO);
    float* resid = (ws_size >= (size_t)WS_RESID + (size_t)QUANT_ELEMS * 4)
                       ? (float*)(ws + WS_RESID) : nullptr;

    hipMemsetAsync(d_ws, 0, 128, stream);
    if (!resid) hipMemsetAsync(d_out, 0, (size_t)out_size * 4, stream);

    vq_norms<<<QD * CDN / 4, 256, 0, stream>>>(cbs, norms);
    vq_cbpack<<<QD * 256, 256, 0, stream>>>(cbs, pkHi, pkLo);   // all levels once

    for (int q = 0; q < QD; q++) {
        const float* cbq = cbs + (size_t)q * CDN * DDIM;
        const float* nq = norms + (size_t)q * CDN;
        const ushort* pH = pkHi + (size_t)q * CDN * DDIM;
        const ushort* pL = pkLo + (size_t)q * CDN * DDIM;
        const float* rsrc;
        const float* qsubA;
        if (resid) {
            rsrc = (q == 0) ? x : resid;
            qsubA = nullptr;
        } else {
            rsrc = x;
            qsubA = quant;
        }
        vq_level_mfma<<<ROWS / BR, TPB, 0, stream>>>(
            rsrc, qsubA, resid, quant, cbq, nq, pH, pL,
            idxo, lossws + q, fbCnt + q, fbList, q);
        vq_fallback<<<128, 256, 0, stream>>>(
            rsrc, qsubA, resid, quant, cbq, nq, idxo, lossws + q,
            fbCnt + q, fbList, q);
    }
    if (resid) {
        vq_quant_final<<<QUANT_ELEMS / 1024, 256, 0, stream>>>(x, resid, quant);
    }
    vq_loss_final<<<1, 64, 0, stream>>>(lossws, losso);
}

// Round 6
// 1498.069 us; speedup vs baseline: 1.6154x; 1.4668x over previous
//
#include <hip/hip_runtime.h>

// Problem constants (fixed by the reference)
#define BD 8
#define SD 4096
#define DDIM 512
#define QD 8
#define CDN 1024
#define ROWS (BD * SD)              // 32768
#define QUANT_ELEMS (ROWS * DDIM)   // 16777216
#define IDX_OFF QUANT_ELEMS
#define LOSS_OFF (QUANT_ELEMS + ROWS * QD)

#define TPB 256
#define NWAVE (TPB / 64)            // 4 waves/block
#define BR 32                       // rows per block
// fp16 single-MFMA pipeline: dist error sigma ~0.02 at the deepest level
// (residual norm grows to ~2200); threshold MARGIN/2 = 0.375 ~ 20 sigma.
// Rows inside the margin go through exact fp32 rescore / full fallback.
#define MARGIN 0.75f

// ws layout (bytes)
#define WS_LOSS 0                   // 8 doubles
#define WS_FBCNT 64                 // 8 ints
#define WS_FBLIST 4096              // 32768 ints (128 KB)
#define WS_NORMS 0x40000            // 32 KB
#define WS_PK 0x100000              // 8 MB (all levels, fp16)
#define WS_RESID 0x1100000          // 64 MB

typedef __attribute__((ext_vector_type(8))) short short8;
typedef __attribute__((ext_vector_type(8))) _Float16 half8;
typedef __attribute__((ext_vector_type(4))) float f32x4;

// ---------------------------------------------------------------- norms
__global__ __launch_bounds__(256) void vq_norms(const float* __restrict__ cb,
                                                float* __restrict__ norms) {
    int code = blockIdx.x * 4 + (threadIdx.x >> 6);
    int lane = threadIdx.x & 63;
    const float4* p = (const float4*)(cb + (size_t)code * DDIM);
    float4 a = p[lane];
    float4 b = p[lane + 64];
    float s = a.x * a.x + a.y * a.y + a.z * a.z + a.w * a.w +
              b.x * b.x + b.y * b.y + b.z * b.z + b.w * b.w;
#pragma unroll
    for (int m = 32; m >= 1; m >>= 1) s += __shfl_xor(s, m);
    if (lane == 0) norms[code] = s;
}

// ---------------------------------------------------------------- cb pack (ALL levels, fp16)
// Frag-major fp16 per level: slot s covers code=tile*16+(lane&15),
// k = kc*32 + (lane>>4)*8 + j.  Wave B-load = 64 lanes x 16B contiguous.
__global__ __launch_bounds__(256) void vq_cbpack(const float* __restrict__ cbs,
                                                 ushort* __restrict__ pk) {
    int sg = blockIdx.x * 256 + threadIdx.x;   // 0..524287 (8 levels x 65536 slots)
    int lvl = sg >> 16;
    int s = sg & 65535;
    int tile = s >> 10;
    int kc = (s >> 6) & 15;
    int ln = s & 63;
    int code = tile * 16 + (ln & 15);
    int k0 = kc * 32 + (ln >> 4) * 8;
    const float* p = cbs + (size_t)lvl * CDN * DDIM + (size_t)code * DDIM + k0;
    float f[8];
    *(float4*)&f[0] = *(const float4*)p;
    *(float4*)&f[4] = *(const float4*)(p + 4);
    _Float16 h[8];
#pragma unroll
    for (int i = 0; i < 8; i++) h[i] = (_Float16)f[i];   // v_cvt_f16_f32, RTNE
    *(short8*)(pk + (size_t)sg * 8) = *(short8*)h;
}

// ---------------------------------------------------------------- fused level (MFMA, fp16)
// R0's proven g-loop structure, workload shrunk by fp16 single-MFMA:
//  - full-K A (fp16) staged in LDS once (32 KB, 1 barrier); 64-step (ct,kc)
//    loop is BARRIER-FREE with depth-1 ping-pong prefetch of A (LDS) and
//    B (L2, fp16 pk) fragments.  8 MFMAs per step (was 24 with bf16 3-split).
//  - registers: aR[2][2] 16 + bR[2][4] 32 + acc[2][4] 32 + td 24 + t12 8
//    + addr ~ 120 raw -> compiles well under the 128 self-cap (R0: 184->108).
//  - LDS ~39 KB -> 3-4 blocks/CU = 12-16 waves (R0 was 2 blocks / 8 waves).
//  - top-3 indices packed as 6-bit tile ids (t12), unpacked after the loop.
// A LDS layout: chunk c=k/8 of row r at  r*512 + ((c ^ (r&7))*8) ushorts —
// XOR swizzle gives <=2 lanes per 4-bank span per 16-lane phase (free, m136).
__global__ __launch_bounds__(TPB, 2) void vq_level_mfma(
    const float* __restrict__ rsrc, const float* __restrict__ qsub,
    float* __restrict__ resid, float* __restrict__ quant,
    const float* __restrict__ cbq, const float* __restrict__ normq,
    const ushort* __restrict__ pk,
    float* __restrict__ idx_out, double* __restrict__ lossq,
    int* __restrict__ fbCnt, int* __restrict__ fbList, int q) {
    __shared__ ushort Ah[BR * 512];          // 32 KB (fp16 bits)
    __shared__ float s_nrm[CDN];             // 4 KB
    __shared__ float m_d1[NWAVE][BR], m_d2[NWAVE][BR], m_d3[NWAVE][BR];
    __shared__ int m_i1[NWAVE][BR], m_i2[NWAVE][BR];
    __shared__ int s_i1[BR], s_i2[BR], s_flag[BR];
    __shared__ double s_part[NWAVE];

    int tid = threadIdx.x;
    int lane = tid & 63;
    int l15 = lane & 15;
    int quad = lane >> 4;
    int cg = tid >> 6;      // wave = code group (0..3)
    int row0 = blockIdx.x * BR;

    for (int i = tid; i < CDN; i += TPB) s_nrm[i] = normq[i];

    // ---- stage full-K A (fp16): 2048 chunks of 8 floats, 8 per thread
#pragma unroll
    for (int i = 0; i < 8; i++) {
        int flat = tid + TPB * i;       // 0..2047
        int row = flat >> 6;
        int c = flat & 63;
        size_t g = (size_t)(row0 + row) * DDIM + c * 8;
        float f[8];
        *(float4*)&f[0] = *(const float4*)(rsrc + g);
        *(float4*)&f[4] = *(const float4*)(rsrc + g + 4);
        if (qsub) {
            float4 w0 = *(const float4*)(qsub + g);
            float4 w1 = *(const float4*)(qsub + g + 4);
            f[0] -= w0.x; f[1] -= w0.y; f[2] -= w0.z; f[3] -= w0.w;
            f[4] -= w1.x; f[5] -= w1.y; f[6] -= w1.z; f[7] -= w1.w;
        }
        _Float16 h[8];
#pragma unroll
        for (int k = 0; k < 8; k++) h[k] = (_Float16)f[k];
        int dst = row * 512 + ((c ^ (row & 7)) * 8);
        *(short8*)(Ah + dst) = *(short8*)h;
    }
    __syncthreads();
    // -------- no __syncthreads below until after the MFMA loop --------

    // per-lane top-3 per slot (rt*4+reg); indices packed: t12 = ti1 | ti2<<6
    float td1[8], td2[8], td3[8];
    int t12[8];
#pragma unroll
    for (int s = 0; s < 8; s++) { td1[s] = 3.4e38f; td2[s] = 3.4e38f; td3[s] = 3.4e38f; t12[s] = 0; }

    half8 aR[2][2], bR[2][4];
    f32x4 acc[2][4];
    int aswz = l15 & 7;                 // (16+l15)&7 == l15&7

#define LOADB(g, p) { int ct_ = (g) >> 4, kc_ = (g) & 15; \
    int base_ = ct_ * 131072 + cg * 32768 + kc_ * 512 + lane * 8; \
    _Pragma("unroll") for (int j = 0; j < 4; j++) \
        bR[p][j] = *(const half8*)(pk + base_ + j * 8192); }

#define LOADA(g, p) { int c0_ = (((g) & 15) * 4 + quad) ^ aswz; \
    aR[p][0] = *(half8*)(Ah + l15 * 512 + c0_ * 8); \
    aR[p][1] = *(half8*)(Ah + (16 + l15) * 512 + c0_ * 8); }

#define BODY(g, p) { \
    if (((g) & 15) == 0) { \
        _Pragma("unroll") for (int rt = 0; rt < 2; rt++) \
        _Pragma("unroll") for (int j = 0; j < 4; j++) acc[rt][j] = (f32x4)0.0f; } \
    if ((g) < 63) { LOADB((g) + 1, 1 - (p)); LOADA((g) + 1, 1 - (p)); } \
    _Pragma("unroll") for (int j = 0; j < 4; j++) { \
        acc[0][j] = __builtin_amdgcn_mfma_f32_16x16x32_f16(aR[p][0], bR[p][j], acc[0][j], 0, 0, 0); \
        acc[1][j] = __builtin_amdgcn_mfma_f32_16x16x32_f16(aR[p][1], bR[p][j], acc[1][j], 0, 0, 0); } \
    if (((g) & 15) == 15) { int ct_ = (g) >> 4; \
        _Pragma("unroll") for (int j = 0; j < 4; j++) { \
            int tile = ct_ * 16 + cg * 4 + j; \
            float nrm = s_nrm[tile * 16 + l15]; \
            _Pragma("unroll") for (int rt = 0; rt < 2; rt++) \
            _Pragma("unroll") for (int reg = 0; reg < 4; reg++) { \
                float v = nrm - 2.0f * acc[rt][j][reg]; \
                int s = rt * 4 + reg; \
                bool b1 = v < td1[s]; bool b2 = v < td2[s]; bool b3 = v < td3[s]; \
                int pb1 = ((t12[s] & 63) << 6) | tile; \
                int pb2 = (tile << 6) | (t12[s] & 63); \
                td3[s] = b2 ? td2[s] : (b3 ? v : td3[s]); \
                t12[s] = b1 ? pb1 : (b2 ? pb2 : t12[s]); \
                td2[s] = b1 ? td1[s] : (b2 ? v : td2[s]); \
                td1[s] = b1 ? v : td1[s]; } } } }

    LOADB(0, 0); LOADA(0, 0);
    for (int gp = 0; gp < 32; gp++) {
        int g0 = gp * 2;
        BODY(g0, 0);
        BODY(g0 + 1, 1);
    }
#undef LOADB
#undef LOADA
#undef BODY

    // unpack tile ids -> full codes (register pressure relaxed here)
    int ti1[8], ti2[8];
#pragma unroll
    for (int s = 0; s < 8; s++) {
        ti1[s] = (t12[s] & 63) * 16 + l15;
        ti2[s] = ((t12[s] >> 6) & 63) * 16 + l15;
    }

    // butterfly merge over 16 l15-lanes (quad preserved)
#pragma unroll
    for (int m = 1; m <= 8; m <<= 1) {
#pragma unroll
        for (int s = 0; s < 8; s++) {
            float o1 = __shfl_xor(td1[s], m); int oi1 = __shfl_xor(ti1[s], m);
            float o2 = __shfl_xor(td2[s], m); int oi2 = __shfl_xor(ti2[s], m);
            float o3 = __shfl_xor(td3[s], m);
            bool aw = (td1[s] < o1) || (td1[s] == o1 && ti1[s] < oi1);
            float w2 = aw ? td2[s] : o2; int wi2 = aw ? ti2[s] : oi2;
            float w3 = aw ? td3[s] : o3;
            float n1 = aw ? td1[s] : o1; int ni1 = aw ? ti1[s] : oi1;
            float p1 = aw ? o1 : td1[s]; int pi1 = aw ? oi1 : ti1[s];
            float p2 = aw ? o2 : td2[s];
            bool sw = (w2 < p1) || (w2 == p1 && wi2 < pi1);
            float n2 = sw ? w2 : p1; int ni2 = sw ? wi2 : pi1;
            float n3 = sw ? fminf(p1, w3) : fminf(w2, p2);
            td1[s] = n1; ti1[s] = ni1; td2[s] = n2; ti2[s] = ni2; td3[s] = n3;
        }
    }

    if (l15 == 0) {
#pragma unroll
        for (int s = 0; s < 8; s++) {
            int row = (s >> 2) * 16 + quad * 4 + (s & 3);
            m_d1[cg][row] = td1[s]; m_i1[cg][row] = ti1[s];
            m_d2[cg][row] = td2[s]; m_i2[cg][row] = ti2[s];
            m_d3[cg][row] = td3[s];
        }
    }
    __syncthreads();

    // 4-way cg merge + flagging (one thread per row)
    if (tid < BR) {
        int r = tid;
        float d1 = m_d1[0][r]; int i1 = m_i1[0][r];
        float d2 = m_d2[0][r]; int i2 = m_i2[0][r];
        float d3 = m_d3[0][r];
#pragma unroll
        for (int c = 1; c < NWAVE; c++) {
            float o1 = m_d1[c][r]; int oi1 = m_i1[c][r];
            float o2 = m_d2[c][r]; int oi2 = m_i2[c][r];
            float o3 = m_d3[c][r];
            bool aw = (d1 < o1) || (d1 == o1 && i1 < oi1);
            float w2 = aw ? d2 : o2; int wi2 = aw ? i2 : oi2;
            float w3 = aw ? d3 : o3;
            float n1 = aw ? d1 : o1; int ni1 = aw ? i1 : oi1;
            float p1 = aw ? o1 : d1; int pi1 = aw ? oi1 : i1;
            float p2 = aw ? o2 : d2;
            bool sw = (w2 < p1) || (w2 == p1 && wi2 < pi1);
            float n2 = sw ? w2 : p1; int ni2 = sw ? wi2 : pi1;
            float n3 = sw ? fminf(p1, w3) : fminf(w2, p2);
            d1 = n1; i1 = ni1; d2 = n2; i2 = ni2; d3 = n3;
        }
        int flag = 0;
        if (d3 - d1 < MARGIN) flag = 2;          // >=3 candidates: full fallback
        else if (d2 - d1 < MARGIN) flag = 1;     // 2 candidates: exact rescore
        s_i1[r] = i1; s_i2[r] = i2; s_flag[r] = flag;
        if (flag == 2) {
            int p = atomicAdd(fbCnt, 1);
            if (p < 32768) fbList[p] = row0 + r;
        }
    }
    __syncthreads();

    // exact fp32 rescore of 2-candidate rows (wave-cooperative)
    for (int r = cg; r < BR; r += NWAVE) {
        if (s_flag[r] != 1) continue;
        int i1 = s_i1[r], i2 = s_i2[r];
        size_t g = (size_t)(row0 + r) * DDIM + lane * 8;
        float rv[8];
        *(float4*)&rv[0] = *(const float4*)(rsrc + g);
        *(float4*)&rv[4] = *(const float4*)(rsrc + g + 4);
        if (qsub) {
            float4 w0 = *(const float4*)(qsub + g);
            float4 w1 = *(const float4*)(qsub + g + 4);
            rv[0] -= w0.x; rv[1] -= w0.y; rv[2] -= w0.z; rv[3] -= w0.w;
            rv[4] -= w1.x; rv[5] -= w1.y; rv[6] -= w1.z; rv[7] -= w1.w;
        }
        float c1[8], c2[8];
        *(float4*)&c1[0] = *(const float4*)(cbq + (size_t)i1 * DDIM + lane * 8);
        *(float4*)&c1[4] = *(const float4*)(cbq + (size_t)i1 * DDIM + lane * 8 + 4);
        *(float4*)&c2[0] = *(const float4*)(cbq + (size_t)i2 * DDIM + lane * 8);
        *(float4*)&c2[4] = *(const float4*)(cbq + (size_t)i2 * DDIM + lane * 8 + 4);
        float e1 = 0.0f, e2 = 0.0f;
#pragma unroll
        for (int i = 0; i < 8; i++) { e1 = fmaf(rv[i], c1[i], e1); e2 = fmaf(rv[i], c2[i], e2); }
#pragma unroll
        for (int m = 32; m >= 1; m >>= 1) { e1 += __shfl_xor(e1, m); e2 += __shfl_xor(e2, m); }
        float dd1 = s_nrm[i1] - 2.0f * e1;
        float dd2 = s_nrm[i2] - 2.0f * e2;
        bool take2 = (dd2 < dd1) || (dd2 == dd1 && i2 < i1);
        if (lane == 0) s_i1[r] = take2 ? i2 : i1;
    }
    __syncthreads();

    if (tid < BR) idx_out[(size_t)(row0 + tid) * QD + q] = (float)s_i1[tid];

    // update phase: resid_new = r - cb[idx]; loss += ||resid_new||^2 (skip fallback rows)
    double ls = 0.0;
#pragma unroll 4
    for (int it = 0; it < 16; it++) {
        int flat = tid + TPB * it;         // 0..4095 float4 chunks
        int row = flat >> 7;
        int c4 = (flat & 127) * 4;
        if (s_flag[row] == 2) continue;
        size_t g = (size_t)(row0 + row) * DDIM + c4;
        float4 r = *(const float4*)(rsrc + g);
        if (qsub) {
            float4 w = *(const float4*)(qsub + g);
            r.x -= w.x; r.y -= w.y; r.z -= w.z; r.w -= w.w;
        }
        float4 cv = *(const float4*)(cbq + (size_t)s_i1[row] * DDIM + c4);
        float4 nr;
        nr.x = r.x - cv.x; nr.y = r.y - cv.y; nr.z = r.z - cv.z; nr.w = r.w - cv.w;
        if (resid) {
            *(float4*)(resid + g) = nr;
        } else {
            float4 qo = *(float4*)(quant + g);
            qo.x += cv.x; qo.y += cv.y; qo.z += cv.z; qo.w += cv.w;
            *(float4*)(quant + g) = qo;
        }
        ls += (double)nr.x * nr.x + (double)nr.y * nr.y +
              (double)nr.z * nr.z + (double)nr.w * nr.w;
    }
#pragma unroll
    for (int m = 32; m >= 1; m >>= 1) ls += __shfl_down(ls, m);
    if ((tid & 63) == 0) s_part[tid >> 6] = ls;
    __syncthreads();
    if (tid == 0) {
        double t = s_part[0] + s_part[1] + s_part[2] + s_part[3];
        atomicAdd(lossq, t);
    }
}

// ---------------------------------------------------------------- full-scan fallback (rare rows)
__global__ __launch_bounds__(256) void vq_fallback(
    const float* __restrict__ rsrc, const float* __restrict__ qsub,
    float* __restrict__ resid, float* __restrict__ quant,
    const float* __restrict__ cbq, const float* __restrict__ normq,
    float* __restrict__ idx_out, double* __restrict__ lossq,
    const int* __restrict__ fbCnt, const int* __restrict__ fbList, int q) {
    __shared__ float r_s[DDIM];
    __shared__ unsigned long long s_best;
    int tid = threadIdx.x;
    int n = *fbCnt; if (n > 32768) n = 32768;
    for (int w = blockIdx.x; w < n; w += gridDim.x) {
        int row = fbList[w];
        if (tid == 0) s_best = ~0ull;
        if (tid < 128) {
            size_t g = (size_t)row * DDIM + tid * 4;
            float4 v = *(const float4*)(rsrc + g);
            if (qsub) {
                float4 x = *(const float4*)(qsub + g);
                v.x -= x.x; v.y -= x.y; v.z -= x.z; v.w -= x.w;
            }
            *(float4*)&r_s[tid * 4] = v;
        }
        __syncthreads();
#pragma unroll
        for (int cc = 0; cc < 4; cc++) {
            int c = tid + 256 * cc;
            float dot = 0.0f;
            for (int k4 = 0; k4 < 128; k4++) {
                float4 cv = *(const float4*)(cbq + (size_t)c * DDIM + k4 * 4);
                float4 rv = *(const float4*)&r_s[k4 * 4];
                dot = fmaf(cv.x, rv.x, dot); dot = fmaf(cv.y, rv.y, dot);
                dot = fmaf(cv.z, rv.z, dot); dot = fmaf(cv.w, rv.w, dot);
            }
            float dist = normq[c] - 2.0f * dot;
            unsigned b = __float_as_uint(dist);
            b = (b & 0x80000000u) ? ~b : (b | 0x80000000u);
            unsigned long long key = (((unsigned long long)b) << 32) | (unsigned)c;
            atomicMin(&s_best, key);
        }
        __syncthreads();
        int idx = (int)(s_best & 0xffffffffull);
        if (tid == 0) idx_out[(size_t)row * QD + q] = (float)idx;
        double ls = 0.0;
        if (tid < 128) {
            size_t g = (size_t)row * DDIM + tid * 4;
            float4 r = *(const float4*)&r_s[tid * 4];
            float4 cv = *(const float4*)(cbq + (size_t)idx * DDIM + tid * 4);
            float4 nr;
            nr.x = r.x - cv.x; nr.y = r.y - cv.y; nr.z = r.z - cv.z; nr.w = r.w - cv.w;
            if (resid) {
                *(float4*)(resid + g) = nr;
            } else {
                float4 qo = *(float4*)(quant + g);
                qo.x += cv.x; qo.y += cv.y; qo.z += cv.z; qo.w += cv.w;
                *(float4*)(quant + g) = qo;
            }
            ls = (double)nr.x * nr.x + (double)nr.y * nr.y +
                 (double)nr.z * nr.z + (double)nr.w * nr.w;
        }
#pragma unroll
        for (int m = 32; m >= 1; m >>= 1) ls += __shfl_down(ls, m);
        if ((tid & 63) == 0 && ls != 0.0) atomicAdd(lossq, ls);
        __syncthreads();
    }
}

// ---------------------------------------------------------------- quant = x - resid_final
__global__ __launch_bounds__(256) void vq_quant_final(const float* __restrict__ x,
                                                      const float* __restrict__ resid,
                                                      float* __restrict__ quant) {
    size_t i = ((size_t)blockIdx.x * 256 + threadIdx.x) * 4;
    float4 xv = *(const float4*)(x + i);
    float4 rv = *(const float4*)(resid + i);
    float4 o;
    o.x = xv.x - rv.x; o.y = xv.y - rv.y; o.z = xv.z - rv.z; o.w = xv.w - rv.w;
    *(float4*)(quant + i) = o;
}

// ---------------------------------------------------------------- finalize losses
__global__ void vq_loss_final(const double* __restrict__ lossws, float* __restrict__ out) {
    int i = threadIdx.x;
    if (i < QD) out[i] = (float)(lossws[i] * (1.0 / (double)((size_t)ROWS * DDIM)));
}

// ---------------------------------------------------------------- launch
extern "C" void kernel_launch(void* const* d_in, const int* in_sizes, int n_in,
                              void* d_out, int out_size, void* d_ws, size_t ws_size,
                              hipStream_t stream) {
    const float* x = (const float*)d_in[0];
    const float* cbs = (const float*)d_in[1];
    float* out = (float*)d_out;
    float* quant = out;
    float* idxo = out + IDX_OFF;
    float* losso = out + LOSS_OFF;

    char* ws = (char*)d_ws;
    double* lossws = (double*)(ws + WS_LOSS);
    int* fbCnt = (int*)(ws + WS_FBCNT);
    int* fbList = (int*)(ws + WS_FBLIST);
    float* norms = (float*)(ws + WS_NORMS);
    ushort* pk = (ushort*)(ws + WS_PK);
    float* resid = (ws_size >= (size_t)WS_RESID + (size_t)QUANT_ELEMS * 4)
                       ? (float*)(ws + WS_RESID) : nullptr;

    hipMemsetAsync(d_ws, 0, 128, stream);
    if (!resid) hipMemsetAsync(d_out, 0, (size_t)out_size * 4, stream);

    vq_norms<<<QD * CDN / 4, 256, 0, stream>>>(cbs, norms);
    vq_cbpack<<<QD * 256, 256, 0, stream>>>(cbs, pk);   // all levels once

    for (int q = 0; q < QD; q++) {
        const float* cbq = cbs + (size_t)q * CDN * DDIM;
        const float* nq = norms + (size_t)q * CDN;
        const ushort* pq = pk + (size_t)q * CDN * DDIM;
        const float* rsrc;
        const float* qsubA;
        if (resid) {
            rsrc = (q == 0) ? x : resid;
            qsubA = nullptr;
        } else {
            rsrc = x;
            qsubA = quant;
        }
        vq_level_mfma<<<ROWS / BR, TPB, 0, stream>>>(
            rsrc, qsubA, resid, quant, cbq, nq, pq,
            idxo, lossws + q, fbCnt + q, fbList, q);
        vq_fallback<<<128, 256, 0, stream>>>(
            rsrc, qsubA, resid, quant, cbq, nq, idxo, lossws + q,
            fbCnt + q, fbList, q);
    }
    if (resid) {
        vq_quant_final<<<QUANT_ELEMS / 1024, 256, 0, stream>>>(x, resid, quant);
    }
    vq_loss_final<<<1, 64, 0, stream>>>(lossws, losso);
}

// Round 12
// 1493.744 us; speedup vs baseline: 1.6201x; 1.0029x over previous
//
#include <hip/hip_runtime.h>

// Problem constants (fixed by the reference)
#define BD 8
#define SD 4096
#define DDIM 512
#define QD 8
#define CDN 1024
#define ROWS (BD * SD)              // 32768
#define QUANT_ELEMS (ROWS * DDIM)   // 16777216
#define IDX_OFF QUANT_ELEMS
#define LOSS_OFF (QUANT_ELEMS + ROWS * QD)

#define TPB 256
#define NWAVE (TPB / 64)            // 4 waves/block
#define BR 32                       // rows per block
// fp16 single-MFMA pipeline: dist error sigma ~0.014 at the worst (first)
// level.  Certainty needs 2*eps <= MARGIN; MARGIN=0.375 keeps eps ~13 sigma
// (R6 validated the same logic at 26 sigma).  Quadratic near-min spacing =>
// flagged rows ~/4 vs MARGIN=0.75 (R6 measured ~400us of full-scan fallback).
#define MARGIN 0.375f

// ws layout (bytes)
#define WS_LOSS 0                   // 8 doubles
#define WS_FBCNT 64                 // 8 ints
#define WS_FBLIST 4096              // 32768 ints (128 KB)
#define WS_NORMS 0x40000            // 32 KB
#define WS_PK 0x100000              // 8 MB (all levels, fp16)
#define WS_RESID 0x1100000          // 64 MB

typedef __attribute__((ext_vector_type(8))) short short8;
typedef __attribute__((ext_vector_type(8))) _Float16 half8;
typedef __attribute__((ext_vector_type(4))) float f32x4;

// ---------------------------------------------------------------- norms
__global__ __launch_bounds__(256) void vq_norms(const float* __restrict__ cb,
                                                float* __restrict__ norms) {
    int code = blockIdx.x * 4 + (threadIdx.x >> 6);
    int lane = threadIdx.x & 63;
    const float4* p = (const float4*)(cb + (size_t)code * DDIM);
    float4 a = p[lane];
    float4 b = p[lane + 64];
    float s = a.x * a.x + a.y * a.y + a.z * a.z + a.w * a.w +
              b.x * b.x + b.y * b.y + b.z * b.z + b.w * b.w;
#pragma unroll
    for (int m = 32; m >= 1; m >>= 1) s += __shfl_xor(s, m);
    if (lane == 0) norms[code] = s;
}

// ---------------------------------------------------------------- cb pack (ALL levels, fp16)
// Frag-major fp16 per level: slot s covers code=tile*16+(lane&15),
// k = kc*32 + (lane>>4)*8 + j.  Wave B-load = 64 lanes x 16B contiguous.
__global__ __launch_bounds__(256) void vq_cbpack(const float* __restrict__ cbs,
                                                 ushort* __restrict__ pk) {
    int sg = blockIdx.x * 256 + threadIdx.x;   // 0..524287 (8 levels x 65536 slots)
    int lvl = sg >> 16;
    int s = sg & 65535;
    int tile = s >> 10;
    int kc = (s >> 6) & 15;
    int ln = s & 63;
    int code = tile * 16 + (ln & 15);
    int k0 = kc * 32 + (ln >> 4) * 8;
    const float* p = cbs + (size_t)lvl * CDN * DDIM + (size_t)code * DDIM + k0;
    float f[8];
    *(float4*)&f[0] = *(const float4*)p;
    *(float4*)&f[4] = *(const float4*)(p + 4);
    _Float16 h[8];
#pragma unroll
    for (int i = 0; i < 8; i++) h[i] = (_Float16)f[i];   // v_cvt_f16_f32, RTNE
    *(short8*)(pk + (size_t)sg * 8) = *(short8*)h;
}

// ---------------------------------------------------------------- fused level (MFMA, fp16)
// R6's verified structure (119us/level, VGPR 88, no spill) — UNCHANGED this
// round; this kernel is the control group while the fallback margin shrinks.
//  - full-K A (fp16) staged in LDS once (32 KB, 1 barrier); 64-step (ct,kc)
//    loop is BARRIER-FREE with depth-1 ping-pong prefetch of A (LDS) and
//    B (L2, fp16 pk) fragments.  8 MFMAs per step.
//  - top-3 indices packed as 6-bit tile ids (t12), unpacked after the loop.
// A LDS layout: chunk c=k/8 of row r at  r*512 + ((c ^ (r&7))*8) ushorts.
__global__ __launch_bounds__(TPB, 2) void vq_level_mfma(
    const float* __restrict__ rsrc, const float* __restrict__ qsub,
    float* __restrict__ resid, float* __restrict__ quant,
    const float* __restrict__ cbq, const float* __restrict__ normq,
    const ushort* __restrict__ pk,
    float* __restrict__ idx_out, double* __restrict__ lossq,
    int* __restrict__ fbCnt, int* __restrict__ fbList, int q) {
    __shared__ ushort Ah[BR * 512];          // 32 KB (fp16 bits)
    __shared__ float s_nrm[CDN];             // 4 KB
    __shared__ float m_d1[NWAVE][BR], m_d2[NWAVE][BR], m_d3[NWAVE][BR];
    __shared__ int m_i1[NWAVE][BR], m_i2[NWAVE][BR];
    __shared__ int s_i1[BR], s_i2[BR], s_flag[BR];
    __shared__ double s_part[NWAVE];

    int tid = threadIdx.x;
    int lane = tid & 63;
    int l15 = lane & 15;
    int quad = lane >> 4;
    int cg = tid >> 6;      // wave = code group (0..3)
    int row0 = blockIdx.x * BR;

    for (int i = tid; i < CDN; i += TPB) s_nrm[i] = normq[i];

    // ---- stage full-K A (fp16): 2048 chunks of 8 floats, 8 per thread
#pragma unroll
    for (int i = 0; i < 8; i++) {
        int flat = tid + TPB * i;       // 0..2047
        int row = flat >> 6;
        int c = flat & 63;
        size_t g = (size_t)(row0 + row) * DDIM + c * 8;
        float f[8];
        *(float4*)&f[0] = *(const float4*)(rsrc + g);
        *(float4*)&f[4] = *(const float4*)(rsrc + g + 4);
        if (qsub) {
            float4 w0 = *(const float4*)(qsub + g);
            float4 w1 = *(const float4*)(qsub + g + 4);
            f[0] -= w0.x; f[1] -= w0.y; f[2] -= w0.z; f[3] -= w0.w;
            f[4] -= w1.x; f[5] -= w1.y; f[6] -= w1.z; f[7] -= w1.w;
        }
        _Float16 h[8];
#pragma unroll
        for (int k = 0; k < 8; k++) h[k] = (_Float16)f[k];
        int dst = row * 512 + ((c ^ (row & 7)) * 8);
        *(short8*)(Ah + dst) = *(short8*)h;
    }
    __syncthreads();
    // -------- no __syncthreads below until after the MFMA loop --------

    // per-lane top-3 per slot (rt*4+reg); indices packed: t12 = ti1 | ti2<<6
    float td1[8], td2[8], td3[8];
    int t12[8];
#pragma unroll
    for (int s = 0; s < 8; s++) { td1[s] = 3.4e38f; td2[s] = 3.4e38f; td3[s] = 3.4e38f; t12[s] = 0; }

    half8 aR[2][2], bR[2][4];
    f32x4 acc[2][4];
    int aswz = l15 & 7;                 // (16+l15)&7 == l15&7

#define LOADB(g, p) { int ct_ = (g) >> 4, kc_ = (g) & 15; \
    int base_ = ct_ * 131072 + cg * 32768 + kc_ * 512 + lane * 8; \
    _Pragma("unroll") for (int j = 0; j < 4; j++) \
        bR[p][j] = *(const half8*)(pk + base_ + j * 8192); }

#define LOADA(g, p) { int c0_ = (((g) & 15) * 4 + quad) ^ aswz; \
    aR[p][0] = *(half8*)(Ah + l15 * 512 + c0_ * 8); \
    aR[p][1] = *(half8*)(Ah + (16 + l15) * 512 + c0_ * 8); }

#define BODY(g, p) { \
    if (((g) & 15) == 0) { \
        _Pragma("unroll") for (int rt = 0; rt < 2; rt++) \
        _Pragma("unroll") for (int j = 0; j < 4; j++) acc[rt][j] = (f32x4)0.0f; } \
    if ((g) < 63) { LOADB((g) + 1, 1 - (p)); LOADA((g) + 1, 1 - (p)); } \
    _Pragma("unroll") for (int j = 0; j < 4; j++) { \
        acc[0][j] = __builtin_amdgcn_mfma_f32_16x16x32_f16(aR[p][0], bR[p][j], acc[0][j], 0, 0, 0); \
        acc[1][j] = __builtin_amdgcn_mfma_f32_16x16x32_f16(aR[p][1], bR[p][j], acc[1][j], 0, 0, 0); } \
    if (((g) & 15) == 15) { int ct_ = (g) >> 4; \
        _Pragma("unroll") for (int j = 0; j < 4; j++) { \
            int tile = ct_ * 16 + cg * 4 + j; \
            float nrm = s_nrm[tile * 16 + l15]; \
            _Pragma("unroll") for (int rt = 0; rt < 2; rt++) \
            _Pragma("unroll") for (int reg = 0; reg < 4; reg++) { \
                float v = nrm - 2.0f * acc[rt][j][reg]; \
                int s = rt * 4 + reg; \
                bool b1 = v < td1[s]; bool b2 = v < td2[s]; bool b3 = v < td3[s]; \
                int pb1 = ((t12[s] & 63) << 6) | tile; \
                int pb2 = (tile << 6) | (t12[s] & 63); \
                td3[s] = b2 ? td2[s] : (b3 ? v : td3[s]); \
                t12[s] = b1 ? pb1 : (b2 ? pb2 : t12[s]); \
                td2[s] = b1 ? td1[s] : (b2 ? v : td2[s]); \
                td1[s] = b1 ? v : td1[s]; } } } }

    LOADB(0, 0); LOADA(0, 0);
    for (int gp = 0; gp < 32; gp++) {
        int g0 = gp * 2;
        BODY(g0, 0);
        BODY(g0 + 1, 1);
    }
#undef LOADB
#undef LOADA
#undef BODY

    // unpack tile ids -> full codes (register pressure relaxed here)
    int ti1[8], ti2[8];
#pragma unroll
    for (int s = 0; s < 8; s++) {
        ti1[s] = (t12[s] & 63) * 16 + l15;
        ti2[s] = ((t12[s] >> 6) & 63) * 16 + l15;
    }

    // butterfly merge over 16 l15-lanes (quad preserved)
#pragma unroll
    for (int m = 1; m <= 8; m <<= 1) {
#pragma unroll
        for (int s = 0; s < 8; s++) {
            float o1 = __shfl_xor(td1[s], m); int oi1 = __shfl_xor(ti1[s], m);
            float o2 = __shfl_xor(td2[s], m); int oi2 = __shfl_xor(ti2[s], m);
            float o3 = __shfl_xor(td3[s], m);
            bool aw = (td1[s] < o1) || (td1[s] == o1 && ti1[s] < oi1);
            float w2 = aw ? td2[s] : o2; int wi2 = aw ? ti2[s] : oi2;
            float w3 = aw ? td3[s] : o3;
            float n1 = aw ? td1[s] : o1; int ni1 = aw ? ti1[s] : oi1;
            float p1 = aw ? o1 : td1[s]; int pi1 = aw ? oi1 : ti1[s];
            float p2 = aw ? o2 : td2[s];
            bool sw = (w2 < p1) || (w2 == p1 && wi2 < pi1);
            float n2 = sw ? w2 : p1; int ni2 = sw ? wi2 : pi1;
            float n3 = sw ? fminf(p1, w3) : fminf(w2, p2);
            td1[s] = n1; ti1[s] = ni1; td2[s] = n2; ti2[s] = ni2; td3[s] = n3;
        }
    }

    if (l15 == 0) {
#pragma unroll
        for (int s = 0; s < 8; s++) {
            int row = (s >> 2) * 16 + quad * 4 + (s & 3);
            m_d1[cg][row] = td1[s]; m_i1[cg][row] = ti1[s];
            m_d2[cg][row] = td2[s]; m_i2[cg][row] = ti2[s];
            m_d3[cg][row] = td3[s];
        }
    }
    __syncthreads();

    // 4-way cg merge + flagging (one thread per row)
    if (tid < BR) {
        int r = tid;
        float d1 = m_d1[0][r]; int i1 = m_i1[0][r];
        float d2 = m_d2[0][r]; int i2 = m_i2[0][r];
        float d3 = m_d3[0][r];
#pragma unroll
        for (int c = 1; c < NWAVE; c++) {
            float o1 = m_d1[c][r]; int oi1 = m_i1[c][r];
            float o2 = m_d2[c][r]; int oi2 = m_i2[c][r];
            float o3 = m_d3[c][r];
            bool aw = (d1 < o1) || (d1 == o1 && i1 < oi1);
            float w2 = aw ? d2 : o2; int wi2 = aw ? i2 : oi2;
            float w3 = aw ? d3 : o3;
            float n1 = aw ? d1 : o1; int ni1 = aw ? i1 : oi1;
            float p1 = aw ? o1 : d1; int pi1 = aw ? oi1 : i1;
            float p2 = aw ? o2 : d2;
            bool sw = (w2 < p1) || (w2 == p1 && wi2 < pi1);
            float n2 = sw ? w2 : p1; int ni2 = sw ? wi2 : pi1;
            float n3 = sw ? fminf(p1, w3) : fminf(w2, p2);
            d1 = n1; i1 = ni1; d2 = n2; i2 = ni2; d3 = n3;
        }
        int flag = 0;
        if (d3 - d1 < MARGIN) flag = 2;          // >=3 candidates: full fallback
        else if (d2 - d1 < MARGIN) flag = 1;     // 2 candidates: exact rescore
        s_i1[r] = i1; s_i2[r] = i2; s_flag[r] = flag;
        if (flag == 2) {
            int p = atomicAdd(fbCnt, 1);
            if (p < 32768) fbList[p] = row0 + r;
        }
    }
    __syncthreads();

    // exact fp32 rescore of 2-candidate rows (wave-cooperative)
    for (int r = cg; r < BR; r += NWAVE) {
        if (s_flag[r] != 1) continue;
        int i1 = s_i1[r], i2 = s_i2[r];
        size_t g = (size_t)(row0 + r) * DDIM + lane * 8;
        float rv[8];
        *(float4*)&rv[0] = *(const float4*)(rsrc + g);
        *(float4*)&rv[4] = *(const float4*)(rsrc + g + 4);
        if (qsub) {
            float4 w0 = *(const float4*)(qsub + g);
            float4 w1 = *(const float4*)(qsub + g + 4);
            rv[0] -= w0.x; rv[1] -= w0.y; rv[2] -= w0.z; rv[3] -= w0.w;
            rv[4] -= w1.x; rv[5] -= w1.y; rv[6] -= w1.z; rv[7] -= w1.w;
        }
        float c1[8], c2[8];
        *(float4*)&c1[0] = *(const float4*)(cbq + (size_t)i1 * DDIM + lane * 8);
        *(float4*)&c1[4] = *(const float4*)(cbq + (size_t)i1 * DDIM + lane * 8 + 4);
        *(float4*)&c2[0] = *(const float4*)(cbq + (size_t)i2 * DDIM + lane * 8);
        *(float4*)&c2[4] = *(const float4*)(cbq + (size_t)i2 * DDIM + lane * 8 + 4);
        float e1 = 0.0f, e2 = 0.0f;
#pragma unroll
        for (int i = 0; i < 8; i++) { e1 = fmaf(rv[i], c1[i], e1); e2 = fmaf(rv[i], c2[i], e2); }
#pragma unroll
        for (int m = 32; m >= 1; m >>= 1) { e1 += __shfl_xor(e1, m); e2 += __shfl_xor(e2, m); }
        float dd1 = s_nrm[i1] - 2.0f * e1;
        float dd2 = s_nrm[i2] - 2.0f * e2;
        bool take2 = (dd2 < dd1) || (dd2 == dd1 && i2 < i1);
        if (lane == 0) s_i1[r] = take2 ? i2 : i1;
    }
    __syncthreads();

    if (tid < BR) idx_out[(size_t)(row0 + tid) * QD + q] = (float)s_i1[tid];

    // update phase: resid_new = r - cb[idx]; loss += ||resid_new||^2 (skip fallback rows)
    double ls = 0.0;
#pragma unroll 4
    for (int it = 0; it < 16; it++) {
        int flat = tid + TPB * it;         // 0..4095 float4 chunks
        int row = flat >> 7;
        int c4 = (flat & 127) * 4;
        if (s_flag[row] == 2) continue;
        size_t g = (size_t)(row0 + row) * DDIM + c4;
        float4 r = *(const float4*)(rsrc + g);
        if (qsub) {
            float4 w = *(const float4*)(qsub + g);
            r.x -= w.x; r.y -= w.y; r.z -= w.z; r.w -= w.w;
        }
        float4 cv = *(const float4*)(cbq + (size_t)s_i1[row] * DDIM + c4);
        float4 nr;
        nr.x = r.x - cv.x; nr.y = r.y - cv.y; nr.z = r.z - cv.z; nr.w = r.w - cv.w;
        if (resid) {
            *(float4*)(resid + g) = nr;
        } else {
            float4 qo = *(float4*)(quant + g);
            qo.x += cv.x; qo.y += cv.y; qo.z += cv.z; qo.w += cv.w;
            *(float4*)(quant + g) = qo;
        }
        ls += (double)nr.x * nr.x + (double)nr.y * nr.y +
              (double)nr.z * nr.z + (double)nr.w * nr.w;
    }
#pragma unroll
    for (int m = 32; m >= 1; m >>= 1) ls += __shfl_down(ls, m);
    if ((tid & 63) == 0) s_part[tid >> 6] = ls;
    __syncthreads();
    if (tid == 0) {
        double t = s_part[0] + s_part[1] + s_part[2] + s_part[3];
        atomicAdd(lossq, t);
    }
}

// ---------------------------------------------------------------- full-scan fallback (rare rows)
__global__ __launch_bounds__(256) void vq_fallback(
    const float* __restrict__ rsrc, const float* __restrict__ qsub,
    float* __restrict__ resid, float* __restrict__ quant,
    const float* __restrict__ cbq, const float* __restrict__ normq,
    float* __restrict__ idx_out, double* __restrict__ lossq,
    const int* __restrict__ fbCnt, const int* __restrict__ fbList, int q) {
    __shared__ float r_s[DDIM];
    __shared__ unsigned long long s_best;
    int tid = threadIdx.x;
    int n = *fbCnt; if (n > 32768) n = 32768;
    for (int w = blockIdx.x; w < n; w += gridDim.x) {
        int row = fbList[w];
        if (tid == 0) s_best = ~0ull;
        if (tid < 128) {
            size_t g = (size_t)row * DDIM + tid * 4;
            float4 v = *(const float4*)(rsrc + g);
            if (qsub) {
                float4 x = *(const float4*)(qsub + g);
                v.x -= x.x; v.y -= x.y; v.z -= x.z; v.w -= x.w;
            }
            *(float4*)&r_s[tid * 4] = v;
        }
        __syncthreads();
#pragma unroll
        for (int cc = 0; cc < 4; cc++) {
            int c = tid + 256 * cc;
            float dot = 0.0f;
            for (int k4 = 0; k4 < 128; k4++) {
                float4 cv = *(const float4*)(cbq + (size_t)c * DDIM + k4 * 4);
                float4 rv = *(const float4*)&r_s[k4 * 4];
                dot = fmaf(cv.x, rv.x, dot); dot = fmaf(cv.y, rv.y, dot);
                dot = fmaf(cv.z, rv.z, dot); dot = fmaf(cv.w, rv.w, dot);
            }
            float dist = normq[c] - 2.0f * dot;
            unsigned b = __float_as_uint(dist);
            b = (b & 0x80000000u) ? ~b : (b | 0x80000000u);
            unsigned long long key = (((unsigned long long)b) << 32) | (unsigned)c;
            atomicMin(&s_best, key);
        }
        __syncthreads();
        int idx = (int)(s_best & 0xffffffffull);
        if (tid == 0) idx_out[(size_t)row * QD + q] = (float)idx;
        double ls = 0.0;
        if (tid < 128) {
            size_t g = (size_t)row * DDIM + tid * 4;
            float4 r = *(const float4*)&r_s[tid * 4];
            float4 cv = *(const float4*)(cbq + (size_t)idx * DDIM + tid * 4);
            float4 nr;
            nr.x = r.x - cv.x; nr.y = r.y - cv.y; nr.z = r.z - cv.z; nr.w = r.w - cv.w;
            if (resid) {
                *(float4*)(resid + g) = nr;
            } else {
                float4 qo = *(float4*)(quant + g);
                qo.x += cv.x; qo.y += cv.y; qo.z += cv.z; qo.w += cv.w;
                *(float4*)(quant + g) = qo;
            }
            ls = (double)nr.x * nr.x + (double)nr.y * nr.y +
                 (double)nr.z * nr.z + (double)nr.w * nr.w;
        }
#pragma unroll
        for (int m = 32; m >= 1; m >>= 1) ls += __shfl_down(ls, m);
        if ((tid & 63) == 0 && ls != 0.0) atomicAdd(lossq, ls);
        __syncthreads();
    }
}

// ---------------------------------------------------------------- quant = x - resid_final
__global__ __launch_bounds__(256) void vq_quant_final(const float* __restrict__ x,
                                                      const float* __restrict__ resid,
                                                      float* __restrict__ quant) {
    size_t i = ((size_t)blockIdx.x * 256 + threadIdx.x) * 4;
    float4 xv = *(const float4*)(x + i);
    float4 rv = *(const float4*)(resid + i);
    float4 o;
    o.x = xv.x - rv.x; o.y = xv.y - rv.y; o.z = xv.z - rv.z; o.w = xv.w - rv.w;
    *(float4*)(quant + i) = o;
}

// ---------------------------------------------------------------- finalize losses
__global__ void vq_loss_final(const double* __restrict__ lossws, float* __restrict__ out) {
    int i = threadIdx.x;
    if (i < QD) out[i] = (float)(lossws[i] * (1.0 / (double)((size_t)ROWS * DDIM)));
}

// ---------------------------------------------------------------- launch
extern "C" void kernel_launch(void* const* d_in, const int* in_sizes, int n_in,
                              void* d_out, int out_size, void* d_ws, size_t ws_size,
                              hipStream_t stream) {
    const float* x = (const float*)d_in[0];
    const float* cbs = (const float*)d_in[1];
    float* out = (float*)d_out;
    float* quant = out;
    float* idxo = out + IDX_OFF;
    float* losso = out + LOSS_OFF;

    char* ws = (char*)d_ws;
    double* lossws = (double*)(ws + WS_LOSS);
    int* fbCnt = (int*)(ws + WS_FBCNT);
    int* fbList = (int*)(ws + WS_FBLIST);
    float* norms = (float*)(ws + WS_NORMS);
    ushort* pk = (ushort*)(ws + WS_PK);
    float* resid = (ws_size >= (size_t)WS_RESID + (size_t)QUANT_ELEMS * 4)
                       ? (float*)(ws + WS_RESID) : nullptr;

    hipMemsetAsync(d_ws, 0, 128, stream);
    if (!resid) hipMemsetAsync(d_out, 0, (size_t)out_size * 4, stream);

    vq_norms<<<QD * CDN / 4, 256, 0, stream>>>(cbs, norms);
    vq_cbpack<<<QD * 256, 256, 0, stream>>>(cbs, pk);   // all levels once

    for (int q = 0; q < QD; q++) {
        const float* cbq = cbs + (size_t)q * CDN * DDIM;
        const float* nq = norms + (size_t)q * CDN;
        const ushort* pq = pk + (size_t)q * CDN * DDIM;
        const float* rsrc;
        const float* qsubA;
        if (resid) {
            rsrc = (q == 0) ? x : resid;
            qsubA = nullptr;
        } else {
            rsrc = x;
            qsubA = quant;
        }
        vq_level_mfma<<<ROWS / BR, TPB, 0, stream>>>(
            rsrc, qsubA, resid, quant, cbq, nq, pq,
            idxo, lossws + q, fbCnt + q, fbList, q);
        vq_fallback<<<256, 256, 0, stream>>>(
            rsrc, qsubA, resid, quant, cbq, nq, idxo, lossws + q,
            fbCnt + q, fbList, q);
    }
    if (resid) {
        vq_quant_final<<<QUANT_ELEMS / 1024, 256, 0, stream>>>(x, resid, quant);
    }
    vq_loss_final<<<1, 64, 0, stream>>>(lossws, losso);
}